// Round 5
// baseline (555.910 us; speedup 1.0000x reference)
//
#include <hip/hip_runtime.h>
#include <hip/hip_bf16.h>
#include <math.h>
#include <stdint.h>

#define NEG_INF_F (-3.4028234663852886e38f)

typedef __bf16 bf16_t;
typedef __bf16 bf16x8 __attribute__((ext_vector_type(8)));
typedef float f32x4 __attribute__((ext_vector_type(4)));
typedef int i32x4 __attribute__((ext_vector_type(4)));
typedef int8_t c8x4 __attribute__((ext_vector_type(4)));

static constexpr int Bb = 2, Ss = 1024, Hid = 4096, Nh = 32, Dh = 128;
static constexpr int Mr = Bb * Ss;   // 2048 token rows
static constexpr int Bh = Bb * Nh;   // 64 (batch*heads)

__device__ __forceinline__ void gload_lds16(const void* g, void* l) {
  __builtin_amdgcn_global_load_lds((const __attribute__((address_space(1))) void*)g,
                                   (__attribute__((address_space(3))) void*)l, 16, 0, 0);
}

__device__ __forceinline__ float wred_max(float v) {
#pragma unroll
  for (int off = 32; off > 0; off >>= 1) v = fmaxf(v, __shfl_xor(v, off));
  return v;
}

// ---------------- RoPE cos/sin tables [S][64] ----------------
__global__ void rope_table_kernel(float* __restrict__ ctab, float* __restrict__ stab) {
  int i = blockIdx.x * 256 + threadIdx.x;   // 0 .. S*64-1
  int srow = i >> 6, d = i & 63;
  float invf = (float)pow(10000.0, -((double)(2 * d) / (double)Dh));
  float ang = (float)srow * invf;           // f32 mul like numpy outer()
  ctab[i] = (float)cos((double)ang);
  stab[i] = (float)sin((double)ang);
}

// ------------- per-row symmetric fake-quant: int8 codes + f32 scale -------------
__global__ __launch_bounds__(256) void quant_rows_kernel(
    const float* __restrict__ in, int8_t* __restrict__ outq,
    float* __restrict__ scale, int ncols, float qmax, float clo, float chi)
{
  const int row = blockIdx.x;
  const float* x = in + (size_t)row * ncols;
  int8_t* o = outq + (size_t)row * ncols;
  const int tid = threadIdx.x;
  const float4* x4 = (const float4*)x;
  const int n4 = ncols >> 2;
  float m = 0.f;
  for (int i = tid; i < n4; i += 256) {
    float4 v = x4[i];
    m = fmaxf(m, fmaxf(fmaxf(fabsf(v.x), fabsf(v.y)), fmaxf(fabsf(v.z), fabsf(v.w))));
  }
  m = wred_max(m);
  __shared__ float red[4];
  if ((tid & 63) == 0) red[tid >> 6] = m;
  __syncthreads();
  m = fmaxf(fmaxf(red[0], red[1]), fmaxf(red[2], red[3]));
  const float s = fmaxf(m / qmax, 1e-8f);
  if (tid == 0) scale[row] = s;
  c8x4* o4 = (c8x4*)o;
  for (int i = tid; i < n4; i += 256) {
    float4 v = x4[i];
    c8x4 r;
    r[0] = (int8_t)(int)fminf(fmaxf(rintf(v.x / s), clo), chi);
    r[1] = (int8_t)(int)fminf(fmaxf(rintf(v.y / s), clo), chi);
    r[2] = (int8_t)(int)fminf(fmaxf(rintf(v.z / s), clo), chi);
    r[3] = (int8_t)(int)fminf(fmaxf(rintf(v.w / s), clo), chi);
    o4[i] = r;
  }
}

// ------------- i8 GEMM: C[m,n] = (sum_k A[m,k]*W[n,k]) * sA[m] * sW[n] -------------
// int8 codes, exact i32 MFMA accumulation (16x16x64_i8), BK=64, global_load_lds w16.
// mode 0: out[m*N+n]   mode 1: out[((b*Nh+h)*Ss+s)*Dh+d]
__global__ __launch_bounds__(256) void gemm_kernel(
    const int8_t* __restrict__ A, const float* __restrict__ sA,
    const int8_t* __restrict__ W, const float* __restrict__ sW,
    float* __restrict__ out, int M, int N, int K, int mode)
{
  __shared__ __align__(16) int8_t As[128 * 64];
  __shared__ __align__(16) int8_t Bs[128 * 64];
  const int tid = threadIdx.x, lane = tid & 63, wid = tid >> 6;
  const int bm = blockIdx.x * 128, bn = blockIdx.y * 128;
  const int wm = wid >> 1, wn = wid & 1;
  const int l15 = lane & 15, kg = lane >> 4;

  // staging: issue r in {0,1}: LDS byte = r*4096 + wid*1024 + lane*16
  //   -> row = r*64 + wid*16 + (lane>>2), kin = (lane&3)*16
  const int srow = wid * 16 + (lane >> 2);
  const int skin = (lane & 3) * 16;
  const int8_t* gA = A + (size_t)(bm + srow) * K + skin;
  const int8_t* gB = W + (size_t)(bn + srow) * K + skin;
  const size_t half = (size_t)64 * K;
  int8_t* lA = As + wid * 1024;   // wave-uniform base; HW adds lane*16B
  int8_t* lB = Bs + wid * 1024;

  i32x4 acc[4][4] = {};
  for (int k0 = 0; k0 < K; k0 += 64) {
    if (k0) __syncthreads();
    gload_lds16(gA + k0, lA);
    gload_lds16(gA + k0 + half, lA + 4096);
    gload_lds16(gB + k0, lB);
    gload_lds16(gB + k0 + half, lB + 4096);
    __syncthreads();
    i32x4 af[4], bw[4];
#pragma unroll
    for (int f = 0; f < 4; ++f) {
      af[f] = *(const i32x4*)&As[(wm * 64 + f * 16 + l15) * 64 + kg * 16];
      bw[f] = *(const i32x4*)&Bs[(wn * 64 + f * 16 + l15) * 64 + kg * 16];
    }
#pragma unroll
    for (int fm = 0; fm < 4; ++fm)
#pragma unroll
      for (int fn = 0; fn < 4; ++fn)
        acc[fm][fn] = __builtin_amdgcn_mfma_i32_16x16x64_i8(af[fm], bw[fn], acc[fm][fn], 0, 0, 0);
  }
#pragma unroll
  for (int fm = 0; fm < 4; ++fm) {
    const int row0 = bm + wm * 64 + fm * 16 + kg * 4;
#pragma unroll
    for (int fn = 0; fn < 4; ++fn) {
      const int col = bn + wn * 64 + fn * 16 + l15;
      const float swv = sW[col];
#pragma unroll
      for (int j = 0; j < 4; ++j) {
        const int row = row0 + j;
        const float val = (float)acc[fm][fn][j] * sA[row] * swv;
        size_t off;
        if (mode == 0) off = (size_t)row * N + col;
        else {
          int b = row >> 10, si = row & 1023, h = col >> 7, d = col & 127;
          off = (((size_t)(b * Nh + h)) * Ss + si) * Dh + d;
        }
        out[off] = val;
      }
    }
  }
}

// ------------- RoPE + per-row(D=128) quant for Q/K; F = ||x|| / (sqrt(sum qi^2) * 128^0.25) -------------
__global__ __launch_bounds__(256) void rope_quant_kernel(
    const float* __restrict__ xin,                 // [Bh*Ss][128]
    const float* __restrict__ ctab, const float* __restrict__ stab,
    int8_t* __restrict__ xq, float* __restrict__ F)
{
  const int gid = blockIdx.x * 4 + (threadIdx.x >> 6);
  const int lane = threadIdx.x & 63;
  const int srow = gid & (Ss - 1);
  const float* x = xin + (size_t)gid * Dh;
  const float xl = x[lane], xh = x[lane + 64];
  const float c = ctab[srow * 64 + lane], sn = stab[srow * 64 + lane];
  // match numpy's unfused mul/add rounding (no fma contraction)
  const float rl = __fsub_rn(__fmul_rn(xl, c), __fmul_rn(xh, sn));
  const float rh = __fadd_rn(__fmul_rn(xh, c), __fmul_rn(xl, sn));
  float ma = fmaxf(fabsf(rl), fabsf(rh));
  float n2 = rl * rl + rh * rh;
#pragma unroll
  for (int off = 32; off > 0; off >>= 1) {
    ma = fmaxf(ma, __shfl_xor(ma, off));
    n2 += __shfl_xor(n2, off);
  }
  const float s = fmaxf(ma / 127.0f, 1e-8f);
  const float ql = fminf(fmaxf(rintf(rl / s), -128.f), 127.f);
  const float qh = fminf(fmaxf(rintf(rh / s), -128.f), 127.f);
  float nq2 = ql * ql + qh * qh;
#pragma unroll
  for (int off = 32; off > 0; off >>= 1) nq2 += __shfl_xor(nq2, off);
  int8_t* o = xq + (size_t)gid * Dh;
  o[lane] = (int8_t)(int)ql;
  o[lane + 64] = (int8_t)(int)qh;
  if (lane == 0) F[gid] = sqrtf(n2 / nq2) * 0.2973017787506803f;  // 1/128^0.25
}

// ------------- V quant: dequant bf16 stored transposed [Bh][128][Ss] via LDS; a2v factor -------------
__global__ __launch_bounds__(256) void vquant_kernel(
    const float* __restrict__ vin, bf16_t* __restrict__ vdqt, float* __restrict__ a2v)
{
  __shared__ bf16_t s_v[128 * 66];
  const int tid = threadIdx.x, lane = tid & 63;
  const int l15 = lane & 15;
  const int qw = (tid >> 6) * 4 + (lane >> 4);   // quarter-wave id 0..15
  const int bh = blockIdx.x >> 4;
  const int t0 = (blockIdx.x & 15) * 64;
  for (int it = 0; it < 4; ++it) {
    const int tt = qw * 4 + it;                   // 0..63
    const size_t gid = (size_t)bh * Ss + t0 + tt;
    const float4 va = *(const float4*)(vin + gid * Dh + l15 * 8);
    const float4 vb = *(const float4*)(vin + gid * Dh + l15 * 8 + 4);
    float m = fmaxf(fmaxf(fmaxf(fabsf(va.x), fabsf(va.y)), fmaxf(fabsf(va.z), fabsf(va.w))),
                    fmaxf(fmaxf(fabsf(vb.x), fabsf(vb.y)), fmaxf(fabsf(vb.z), fabsf(vb.w))));
    float n2 = va.x * va.x + va.y * va.y + va.z * va.z + va.w * va.w +
               vb.x * vb.x + vb.y * vb.y + vb.z * vb.z + vb.w * vb.w;
#pragma unroll
    for (int off = 1; off < 16; off <<= 1) {
      m = fmaxf(m, __shfl_xor(m, off));
      n2 += __shfl_xor(n2, off);
    }
    const float s = fmaxf(m / 127.0f, 1e-8f);
    float q[8] = {va.x, va.y, va.z, va.w, vb.x, vb.y, vb.z, vb.w};
    float nq2 = 0.f;
#pragma unroll
    for (int e = 0; e < 8; ++e) {
      q[e] = fminf(fmaxf(rintf(q[e] / s), -128.f), 127.f);
      nq2 += q[e] * q[e];
      s_v[(l15 * 8 + e) * 66 + tt] = (bf16_t)(q[e] * s);
    }
#pragma unroll
    for (int off = 1; off < 16; off <<= 1) nq2 += __shfl_xor(nq2, off);
    if (l15 == 0) a2v[gid] = s * sqrtf(nq2) / sqrtf(n2);
  }
  __syncthreads();
  // coalesced write-out: thread -> (row, half): 32 bf16 = 64 B
  const int r = tid >> 1, hc = (tid & 1) * 32;
  const bf16_t* src = &s_v[r * 66 + hc];
  bf16_t* dst = vdqt + ((size_t)bh * Dh + r) * Ss + t0 + hc;
#pragma unroll
  for (int k = 0; k < 4; ++k) {
    bf16x8 t;
#pragma unroll
    for (int e = 0; e < 8; ++e) t[e] = src[k * 8 + e];
    *(bf16x8*)(dst + k * 8) = t;
  }
}

// ------------- fused attention: i8 QK^T (causal, recompute) -> softmax -> P-quant -> bf16 PV -------------
// No score array kept live: pass A computes row max only; pass B recomputes the
// (cheap, L2-hot) i8 MFMAs and does exp + P-quant. Avoids the 64-VGPR spill.
__global__ __launch_bounds__(256, 2) void attn_kernel(
    const int8_t* __restrict__ qq, const int8_t* __restrict__ kq,
    const bf16_t* __restrict__ vdqt,
    const float* __restrict__ Fq, const float* __restrict__ Fk,
    const float* __restrict__ A2v, float* __restrict__ oattn)
{
  const int bh = blockIdx.y, b = bh >> 5, h = bh & 31;
  const int q0 = blockIdx.x * 16;
  const int nfc2 = ((int)blockIdx.x + 2) & ~1;   // 16-col chunks (even count)
  const int tid = threadIdx.x, lane = tid & 63, wid = tid >> 6;
  const int l15 = lane & 15, kg = lane >> 4, kof = kg * 8;
  __shared__ __align__(16) bf16_t s_pq[16][1024];
  __shared__ float s_rmax[4][16];
  __shared__ float s_rsum[4][16];

  // contiguous per-wave chunk range: wave wid handles [c0, c0+cn)
  const int cbase = nfc2 >> 2, crem = nfc2 & 3;
  const int cn = cbase + (wid < crem ? 1 : 0);
  const int c0 = wid * cbase + (wid < crem ? wid : crem);

  const size_t bhS = (size_t)bh * Ss;
  const int8_t* qbase = qq + (bhS + q0) * Dh;
  const i32x4 aq0 = *(const i32x4*)(qbase + l15 * Dh + kg * 16);
  const i32x4 aq1 = *(const i32x4*)(qbase + l15 * Dh + 64 + kg * 16);
  float fq[4];
#pragma unroll
  for (int j = 0; j < 4; ++j) fq[j] = Fq[bhS + q0 + kg * 4 + j];
  const int qrow0 = q0 + kg * 4;

  // --- pass A: QK^T, track row max only (nothing kept live per chunk) ---
  float pm[4] = {NEG_INF_F, NEG_INF_F, NEG_INF_F, NEG_INF_F};
  for (int i = 0; i < cn; ++i) {
    const int kc = (c0 + i) * 16;
    const int8_t* kbase = kq + (bhS + kc) * Dh;
    i32x4 bk0 = *(const i32x4*)(kbase + l15 * Dh + kg * 16);
    i32x4 bk1 = *(const i32x4*)(kbase + l15 * Dh + 64 + kg * 16);
    i32x4 c = {};
    c = __builtin_amdgcn_mfma_i32_16x16x64_i8(aq0, bk0, c, 0, 0, 0);
    c = __builtin_amdgcn_mfma_i32_16x16x64_i8(aq1, bk1, c, 0, 0, 0);
    const int col = kc + l15;
    const float fk = Fk[bhS + col];
#pragma unroll
    for (int j = 0; j < 4; ++j) {
      const float v = (col <= qrow0 + j) ? (float)c[j] * fq[j] * fk : NEG_INF_F;
      pm[j] = fmaxf(pm[j], v);
    }
  }
#pragma unroll
  for (int j = 0; j < 4; ++j) {
#pragma unroll
    for (int off = 1; off < 16; off <<= 1) pm[j] = fmaxf(pm[j], __shfl_xor(pm[j], off));
  }
  if (l15 == 0) {
#pragma unroll
    for (int j = 0; j < 4; ++j) s_rmax[wid][kg * 4 + j] = pm[j];
  }
  __syncthreads();
  float mrow[4], zp[4] = {0.f, 0.f, 0.f, 0.f};
#pragma unroll
  for (int j = 0; j < 4; ++j) {
    const int r = kg * 4 + j;
    mrow[j] = fmaxf(fmaxf(s_rmax[0][r], s_rmax[1][r]), fmaxf(s_rmax[2][r], s_rmax[3][r]));
  }
  // --- pass B: recompute scores (bit-identical), exp, Z partial, P-quant to LDS ---
  for (int i = 0; i < cn; ++i) {
    const int kc = (c0 + i) * 16;
    const int8_t* kbase = kq + (bhS + kc) * Dh;
    i32x4 bk0 = *(const i32x4*)(kbase + l15 * Dh + kg * 16);
    i32x4 bk1 = *(const i32x4*)(kbase + l15 * Dh + 64 + kg * 16);
    i32x4 c = {};
    c = __builtin_amdgcn_mfma_i32_16x16x64_i8(aq0, bk0, c, 0, 0, 0);
    c = __builtin_amdgcn_mfma_i32_16x16x64_i8(aq1, bk1, c, 0, 0, 0);
    const int col = kc + l15;
    const float fk = Fk[bhS + col];
#pragma unroll
    for (int j = 0; j < 4; ++j) {
      const float v = (col <= qrow0 + j) ? (float)c[j] * fq[j] * fk : NEG_INF_F;
      const float e = __expf(v - mrow[j]);   // masked -> exp(-huge) = 0 exactly
      zp[j] += e;
      const int r = kg * 4 + j;
      s_pq[r][col ^ ((r & 7) << 3)] = (bf16_t)fminf(rintf(127.0f * e), 127.0f);
    }
  }
#pragma unroll
  for (int j = 0; j < 4; ++j) {
#pragma unroll
    for (int off = 1; off < 16; off <<= 1) zp[j] += __shfl_xor(zp[j], off);
  }
  if (l15 == 0) {
#pragma unroll
    for (int j = 0; j < 4; ++j) s_rsum[wid][kg * 4 + j] = zp[j];
  }
  __syncthreads();
  float osc[4];
#pragma unroll
  for (int j = 0; j < 4; ++j) {
    const int r = kg * 4 + j;
    const float Z = ((s_rsum[0][r] + s_rsum[1][r]) + (s_rsum[2][r] + s_rsum[3][r]));
    const float pmax = 1.0f / Z;                  // softmax row max
    const float sp = fmaxf(pmax / 127.0f, 1e-8f); // p scale
    osc[j] = sp / A2v[bhS + q0 + r];
  }
  // --- PV over causal range: this wave owns 32 of 128 d-columns ---
  const int nkk = nfc2 >> 1;
  f32x4 oacc[2] = {};
  const int d0 = wid * 32;
  const bf16_t* vb0 = vdqt + ((size_t)bh * Dh + d0 + l15) * Ss;
  const bf16_t* vb1 = vb0 + (size_t)16 * Ss;
  for (int kk = 0; kk < nkk; ++kk) {
    const int kidx = kk * 32 + kof;
    bf16x8 ap = *(const bf16x8*)&s_pq[l15][kidx ^ ((l15 & 7) << 3)];
    bf16x8 b0 = *(const bf16x8*)(vb0 + kidx);
    bf16x8 b1 = *(const bf16x8*)(vb1 + kidx);
    oacc[0] = __builtin_amdgcn_mfma_f32_16x16x32_bf16(ap, b0, oacc[0], 0, 0, 0);
    oacc[1] = __builtin_amdgcn_mfma_f32_16x16x32_bf16(ap, b1, oacc[1], 0, 0, 0);
  }
#pragma unroll
  for (int f = 0; f < 2; ++f) {
    const int col = d0 + f * 16 + l15;
#pragma unroll
    for (int j = 0; j < 4; ++j) {
      const int r = kg * 4 + j;
      oattn[((size_t)b * Ss + q0 + r) * Hid + h * Dh + col] = oacc[f][j] * osc[j];
    }
  }
}

extern "C" void kernel_launch(void* const* d_in, const int* in_sizes, int n_in,
                              void* d_out, int out_size, void* d_ws, size_t ws_size,
                              hipStream_t stream)
{
  const float* hidden = (const float*)d_in[0];
  const float* wq = (const float*)d_in[1];
  const float* wk = (const float*)d_in[2];
  const float* wv = (const float*)d_in[3];
  const float* wo = (const float*)d_in[4];
  float* out = (float*)d_out;

  // ---- workspace layout with aggressive reuse (~90 MiB total) ----
  char* p = (char*)d_ws;
  auto alloc = [&](size_t bytes) -> char* {
    char* r = p; p += (bytes + 255) & ~(size_t)255; return r;
  };
  int8_t* xq   = (int8_t*)alloc((size_t)Mr * Hid);                     // act codes; later reused for oq
  int8_t* wbuf = (int8_t*)alloc((size_t)Hid * Hid);                    // shared weight codes
  float*  projf= (float*) alloc((size_t)Bh * Ss * Dh * sizeof(float)); // shared proj out; later oat
  int8_t* qqb  = (int8_t*)alloc((size_t)Bh * Ss * Dh);
  int8_t* kqb  = (int8_t*)alloc((size_t)Bh * Ss * Dh);
  bf16_t* vdqt = (bf16_t*)alloc((size_t)Bh * Dh * Ss * sizeof(bf16_t));
  float* sxa = (float*)alloc((size_t)Mr * sizeof(float));
  float* sw  = (float*)alloc((size_t)Hid * sizeof(float));
  float* Fq  = (float*)alloc((size_t)Bh * Ss * sizeof(float));
  float* Fk  = (float*)alloc((size_t)Bh * Ss * sizeof(float));
  float* A2v = (float*)alloc((size_t)Bh * Ss * sizeof(float));
  float* soa = (float*)alloc((size_t)Mr * sizeof(float));
  float* ctab = (float*)alloc((size_t)Ss * 64 * sizeof(float));
  float* stab = (float*)alloc((size_t)Ss * 64 * sizeof(float));
  float*  oat = projf;           // projf dead after vquant
  int8_t* oq  = xq;              // xq dead after the three projections

  rope_table_kernel<<<Ss * 64 / 256, 256, 0, stream>>>(ctab, stab);
  quant_rows_kernel<<<Mr, 256, 0, stream>>>(hidden, xq, sxa, Hid, 127.f, -128.f, 127.f);

  dim3 gg(Mr / 128, Hid / 128);
  // Q
  quant_rows_kernel<<<Hid, 256, 0, stream>>>(wq, wbuf, sw, Hid, 7.f, -8.f, 7.f);
  gemm_kernel<<<gg, 256, 0, stream>>>(xq, sxa, wbuf, sw, projf, Mr, Hid, Hid, 1);
  rope_quant_kernel<<<Bh * Ss / 4, 256, 0, stream>>>(projf, ctab, stab, qqb, Fq);
  // K
  quant_rows_kernel<<<Hid, 256, 0, stream>>>(wk, wbuf, sw, Hid, 7.f, -8.f, 7.f);
  gemm_kernel<<<gg, 256, 0, stream>>>(xq, sxa, wbuf, sw, projf, Mr, Hid, Hid, 1);
  rope_quant_kernel<<<Bh * Ss / 4, 256, 0, stream>>>(projf, ctab, stab, kqb, Fk);
  // V
  quant_rows_kernel<<<Hid, 256, 0, stream>>>(wv, wbuf, sw, Hid, 7.f, -8.f, 7.f);
  gemm_kernel<<<gg, 256, 0, stream>>>(xq, sxa, wbuf, sw, projf, Mr, Hid, Hid, 1);
  vquant_kernel<<<Bh * 16, 256, 0, stream>>>(projf, vdqt, A2v);

  dim3 ga(Ss / 16, Bh);
  attn_kernel<<<ga, 256, 0, stream>>>(qqb, kqb, vdqt, Fq, Fk, A2v, oat);

  quant_rows_kernel<<<Mr, 256, 0, stream>>>(oat, oq, soa, Hid, 127.f, -128.f, 127.f);
  quant_rows_kernel<<<Hid, 256, 0, stream>>>(wo, wbuf, sw, Hid, 7.f, -8.f, 7.f);
  gemm_kernel<<<gg, 256, 0, stream>>>(oq, soa, wbuf, sw, out, Mr, Hid, Hid, 0);
}

// Round 6
// 469.982 us; speedup vs baseline: 1.1828x; 1.1828x over previous
//
#include <hip/hip_runtime.h>
#include <hip/hip_bf16.h>
#include <math.h>
#include <stdint.h>

#define NEG_INF_F (-3.4028234663852886e38f)

typedef __bf16 bf16_t;
typedef __bf16 bf16x8 __attribute__((ext_vector_type(8)));
typedef float f32x4 __attribute__((ext_vector_type(4)));
typedef float f32x16 __attribute__((ext_vector_type(16)));
typedef int i32x4 __attribute__((ext_vector_type(4)));
typedef int i32x16 __attribute__((ext_vector_type(16)));
typedef int8_t c8x4 __attribute__((ext_vector_type(4)));

static constexpr int Bb = 2, Ss = 1024, Hid = 4096, Nh = 32, Dh = 128;
static constexpr int Mr = Bb * Ss;   // 2048 token rows
static constexpr int Bh = Bb * Nh;   // 64 (batch*heads)

__device__ __forceinline__ void gload_lds16(const void* g, void* l) {
  __builtin_amdgcn_global_load_lds((const __attribute__((address_space(1))) void*)g,
                                   (__attribute__((address_space(3))) void*)l, 16, 0, 0);
}

__device__ __forceinline__ float wred_max(float v) {
#pragma unroll
  for (int off = 32; off > 0; off >>= 1) v = fmaxf(v, __shfl_xor(v, off));
  return v;
}

__device__ __forceinline__ unsigned pkbf(float a, float b) {
  unsigned short ua = __builtin_bit_cast(unsigned short, (bf16_t)a);
  unsigned short ub = __builtin_bit_cast(unsigned short, (bf16_t)b);
  return (unsigned)ua | ((unsigned)ub << 16);
}

// ---------------- RoPE cos/sin tables [S][64] ----------------
__global__ void rope_table_kernel(float* __restrict__ ctab, float* __restrict__ stab) {
  int i = blockIdx.x * 256 + threadIdx.x;   // 0 .. S*64-1
  int srow = i >> 6, d = i & 63;
  float invf = (float)pow(10000.0, -((double)(2 * d) / (double)Dh));
  float ang = (float)srow * invf;           // f32 mul like numpy outer()
  ctab[i] = (float)cos((double)ang);
  stab[i] = (float)sin((double)ang);
}

// ------------- per-row symmetric fake-quant: int8 codes + f32 scale -------------
__global__ __launch_bounds__(256) void quant_rows_kernel(
    const float* __restrict__ in, int8_t* __restrict__ outq,
    float* __restrict__ scale, int ncols, float qmax, float clo, float chi)
{
  const int row = blockIdx.x;
  const float* x = in + (size_t)row * ncols;
  int8_t* o = outq + (size_t)row * ncols;
  const int tid = threadIdx.x;
  const float4* x4 = (const float4*)x;
  const int n4 = ncols >> 2;
  float m = 0.f;
  for (int i = tid; i < n4; i += 256) {
    float4 v = x4[i];
    m = fmaxf(m, fmaxf(fmaxf(fabsf(v.x), fabsf(v.y)), fmaxf(fabsf(v.z), fabsf(v.w))));
  }
  m = wred_max(m);
  __shared__ float red[4];
  if ((tid & 63) == 0) red[tid >> 6] = m;
  __syncthreads();
  m = fmaxf(fmaxf(red[0], red[1]), fmaxf(red[2], red[3]));
  const float s = fmaxf(m / qmax, 1e-8f);
  if (tid == 0) scale[row] = s;
  c8x4* o4 = (c8x4*)o;
  for (int i = tid; i < n4; i += 256) {
    float4 v = x4[i];
    c8x4 r;
    r[0] = (int8_t)(int)fminf(fmaxf(rintf(v.x / s), clo), chi);
    r[1] = (int8_t)(int)fminf(fmaxf(rintf(v.y / s), clo), chi);
    r[2] = (int8_t)(int)fminf(fmaxf(rintf(v.z / s), clo), chi);
    r[3] = (int8_t)(int)fminf(fmaxf(rintf(v.w / s), clo), chi);
    o4[i] = r;
  }
}

// ------------- i8 GEMM: C[m,n] = (sum_k A[m,k]*W[n,k]) * sA[m] * sW[n] -------------
__global__ __launch_bounds__(256) void gemm_kernel(
    const int8_t* __restrict__ A, const float* __restrict__ sA,
    const int8_t* __restrict__ W, const float* __restrict__ sW,
    float* __restrict__ out, int M, int N, int K, int mode)
{
  __shared__ __align__(16) int8_t As[128 * 64];
  __shared__ __align__(16) int8_t Bs[128 * 64];
  const int tid = threadIdx.x, lane = tid & 63, wid = tid >> 6;
  const int bm = blockIdx.x * 128, bn = blockIdx.y * 128;
  const int wm = wid >> 1, wn = wid & 1;
  const int l15 = lane & 15, kg = lane >> 4;

  const int srow = wid * 16 + (lane >> 2);
  const int skin = (lane & 3) * 16;
  const int8_t* gA = A + (size_t)(bm + srow) * K + skin;
  const int8_t* gB = W + (size_t)(bn + srow) * K + skin;
  const size_t half = (size_t)64 * K;
  int8_t* lA = As + wid * 1024;   // wave-uniform base; HW adds lane*16B
  int8_t* lB = Bs + wid * 1024;

  i32x4 acc[4][4] = {};
  for (int k0 = 0; k0 < K; k0 += 64) {
    if (k0) __syncthreads();
    gload_lds16(gA + k0, lA);
    gload_lds16(gA + k0 + half, lA + 4096);
    gload_lds16(gB + k0, lB);
    gload_lds16(gB + k0 + half, lB + 4096);
    __syncthreads();
    i32x4 af[4], bw[4];
#pragma unroll
    for (int f = 0; f < 4; ++f) {
      af[f] = *(const i32x4*)&As[(wm * 64 + f * 16 + l15) * 64 + kg * 16];
      bw[f] = *(const i32x4*)&Bs[(wn * 64 + f * 16 + l15) * 64 + kg * 16];
    }
#pragma unroll
    for (int fm = 0; fm < 4; ++fm)
#pragma unroll
      for (int fn = 0; fn < 4; ++fn)
        acc[fm][fn] = __builtin_amdgcn_mfma_i32_16x16x64_i8(af[fm], bw[fn], acc[fm][fn], 0, 0, 0);
  }
#pragma unroll
  for (int fm = 0; fm < 4; ++fm) {
    const int row0 = bm + wm * 64 + fm * 16 + kg * 4;
#pragma unroll
    for (int fn = 0; fn < 4; ++fn) {
      const int col = bn + wn * 64 + fn * 16 + l15;
      const float swv = sW[col];
#pragma unroll
      for (int j = 0; j < 4; ++j) {
        const int row = row0 + j;
        const float val = (float)acc[fm][fn][j] * sA[row] * swv;
        size_t off;
        if (mode == 0) off = (size_t)row * N + col;
        else {
          int b = row >> 10, si = row & 1023, h = col >> 7, d = col & 127;
          off = (((size_t)(b * Nh + h)) * Ss + si) * Dh + d;
        }
        out[off] = val;
      }
    }
  }
}

// ------------- RoPE + per-row(D=128) quant for Q/K -------------
__global__ __launch_bounds__(256) void rope_quant_kernel(
    const float* __restrict__ xin,
    const float* __restrict__ ctab, const float* __restrict__ stab,
    int8_t* __restrict__ xq, float* __restrict__ F)
{
  const int gid = blockIdx.x * 4 + (threadIdx.x >> 6);
  const int lane = threadIdx.x & 63;
  const int srow = gid & (Ss - 1);
  const float* x = xin + (size_t)gid * Dh;
  const float xl = x[lane], xh = x[lane + 64];
  const float c = ctab[srow * 64 + lane], sn = stab[srow * 64 + lane];
  const float rl = __fsub_rn(__fmul_rn(xl, c), __fmul_rn(xh, sn));
  const float rh = __fadd_rn(__fmul_rn(xh, c), __fmul_rn(xl, sn));
  float ma = fmaxf(fabsf(rl), fabsf(rh));
  float n2 = rl * rl + rh * rh;
#pragma unroll
  for (int off = 32; off > 0; off >>= 1) {
    ma = fmaxf(ma, __shfl_xor(ma, off));
    n2 += __shfl_xor(n2, off);
  }
  const float s = fmaxf(ma / 127.0f, 1e-8f);
  const float ql = fminf(fmaxf(rintf(rl / s), -128.f), 127.f);
  const float qh = fminf(fmaxf(rintf(rh / s), -128.f), 127.f);
  float nq2 = ql * ql + qh * qh;
#pragma unroll
  for (int off = 32; off > 0; off >>= 1) nq2 += __shfl_xor(nq2, off);
  int8_t* o = xq + (size_t)gid * Dh;
  o[lane] = (int8_t)(int)ql;
  o[lane + 64] = (int8_t)(int)qh;
  if (lane == 0) F[gid] = sqrtf(n2 / nq2) * 0.2973017787506803f;  // 1/128^0.25
}

// ------------- V quant: dequant bf16 stored transposed [Bh][128][Ss] via LDS -------------
__global__ __launch_bounds__(256) void vquant_kernel(
    const float* __restrict__ vin, bf16_t* __restrict__ vdqt, float* __restrict__ a2v)
{
  __shared__ bf16_t s_v[128 * 66];
  const int tid = threadIdx.x, lane = tid & 63;
  const int l15 = lane & 15;
  const int qw = (tid >> 6) * 4 + (lane >> 4);
  const int bh = blockIdx.x >> 4;
  const int t0 = (blockIdx.x & 15) * 64;
  for (int it = 0; it < 4; ++it) {
    const int tt = qw * 4 + it;
    const size_t gid = (size_t)bh * Ss + t0 + tt;
    const float4 va = *(const float4*)(vin + gid * Dh + l15 * 8);
    const float4 vb = *(const float4*)(vin + gid * Dh + l15 * 8 + 4);
    float m = fmaxf(fmaxf(fmaxf(fabsf(va.x), fabsf(va.y)), fmaxf(fabsf(va.z), fabsf(va.w))),
                    fmaxf(fmaxf(fabsf(vb.x), fabsf(vb.y)), fmaxf(fabsf(vb.z), fabsf(vb.w))));
    float n2 = va.x * va.x + va.y * va.y + va.z * va.z + va.w * va.w +
               vb.x * vb.x + vb.y * vb.y + vb.z * vb.z + vb.w * vb.w;
#pragma unroll
    for (int off = 1; off < 16; off <<= 1) {
      m = fmaxf(m, __shfl_xor(m, off));
      n2 += __shfl_xor(n2, off);
    }
    const float s = fmaxf(m / 127.0f, 1e-8f);
    float q[8] = {va.x, va.y, va.z, va.w, vb.x, vb.y, vb.z, vb.w};
    float nq2 = 0.f;
#pragma unroll
    for (int e = 0; e < 8; ++e) {
      q[e] = fminf(fmaxf(rintf(q[e] / s), -128.f), 127.f);
      nq2 += q[e] * q[e];
      s_v[(l15 * 8 + e) * 66 + tt] = (bf16_t)(q[e] * s);
    }
#pragma unroll
    for (int off = 1; off < 16; off <<= 1) nq2 += __shfl_xor(nq2, off);
    if (l15 == 0) a2v[gid] = s * sqrtf(nq2) / sqrtf(n2);
  }
  __syncthreads();
  const int r = tid >> 1, hc = (tid & 1) * 32;
  const bf16_t* src = &s_v[r * 66 + hc];
  bf16_t* dst = vdqt + ((size_t)bh * Dh + r) * Ss + t0 + hc;
#pragma unroll
  for (int k = 0; k < 4; ++k) {
    bf16x8 t;
#pragma unroll
    for (int e = 0; e < 8; ++e) t[e] = src[k * 8 + e];
    *(bf16x8*)(dst + k * 8) = t;
  }
}

// ------------- fused attention, swapped-operand in-register structure -------------
// grid (Bh, Ss/128); 4 waves/block; wave owns 32 q-rows (q0 = by*128 + wid*32).
// QK^T: mfma_i32_32x32x32_i8(A=K, B=Q) -> D[k][q], q = lane&31 (lane-local row).
// Pass A: row max (in-reg + 1 shfl). Pass B: recompute + exp + P codes packed to
// bf16 in-reg, shfl-exchange into PV A-frag; PV: mfma_f32_32x32x16_bf16(P, V^T).
#define KR(r) (((r) & 3) + 8 * ((r) >> 2) + 4 * hi)
__global__ __launch_bounds__(256, 2) void attn_kernel(
    const int8_t* __restrict__ qq, const int8_t* __restrict__ kq,
    const bf16_t* __restrict__ vdqt,
    const float* __restrict__ Fq, const float* __restrict__ Fk,
    const float* __restrict__ A2v, float* __restrict__ oattn)
{
  const int bh = blockIdx.x, b = bh >> 5, h = bh & 31;
  const int wid = threadIdx.x >> 6, lane = threadIdx.x & 63;
  const int l31 = lane & 31, hi = lane >> 5;
  const int q0 = blockIdx.y * 128 + wid * 32;
  const size_t bhS = (size_t)bh * Ss;
  __shared__ float s_osc[4][32];

  // Q B-fragments (col = q = q0 + l31), 4 d-chunks of 32
  const int8_t* qrow = qq + (bhS + q0 + l31) * Dh + hi * 16;
  i32x4 qf[4];
#pragma unroll
  for (int c = 0; c < 4; ++c) qf[c] = *(const i32x4*)(qrow + c * 32);
  const float fq = Fq[bhS + q0 + l31];
  const int qcol = q0 + l31;
  const int nt = q0 / 32 + 1;           // causal 32-wide k-tiles

  // ---- pass A: row max ----
  float m = NEG_INF_F;
  for (int t = 0; t < nt; ++t) {
    const int kb = t * 32;
    const int8_t* krow = kq + (bhS + kb + l31) * Dh + hi * 16;
    i32x16 c = {};
    c = __builtin_amdgcn_mfma_i32_32x32x32_i8(*(const i32x4*)(krow),      qf[0], c, 0, 0, 0);
    c = __builtin_amdgcn_mfma_i32_32x32x32_i8(*(const i32x4*)(krow + 32), qf[1], c, 0, 0, 0);
    c = __builtin_amdgcn_mfma_i32_32x32x32_i8(*(const i32x4*)(krow + 64), qf[2], c, 0, 0, 0);
    c = __builtin_amdgcn_mfma_i32_32x32x32_i8(*(const i32x4*)(krow + 96), qf[3], c, 0, 0, 0);
    float4 fk4[4];
#pragma unroll
    for (int g = 0; g < 4; ++g) fk4[g] = *(const float4*)&Fk[bhS + kb + g * 8 + 4 * hi];
    if (t == nt - 1) {
#pragma unroll
      for (int r = 0; r < 16; ++r) {
        const float v = (float)c[r] * fq * ((const float*)&fk4[r >> 2])[r & 3];
        if (kb + KR(r) <= qcol) m = fmaxf(m, v);
      }
    } else {
#pragma unroll
      for (int r = 0; r < 16; ++r)
        m = fmaxf(m, (float)c[r] * fq * ((const float*)&fk4[r >> 2])[r & 3]);
    }
  }
  m = fmaxf(m, __shfl_xor(m, 32));

  // ---- pass B: recompute + exp + P-codes -> PV (fused per tile) ----
  float z = 0.f;
  f32x16 oacc[4] = {};
  for (int t = 0; t < nt; ++t) {
    const int kb = t * 32;
    const int8_t* krow = kq + (bhS + kb + l31) * Dh + hi * 16;
    i32x16 c = {};
    c = __builtin_amdgcn_mfma_i32_32x32x32_i8(*(const i32x4*)(krow),      qf[0], c, 0, 0, 0);
    c = __builtin_amdgcn_mfma_i32_32x32x32_i8(*(const i32x4*)(krow + 32), qf[1], c, 0, 0, 0);
    c = __builtin_amdgcn_mfma_i32_32x32x32_i8(*(const i32x4*)(krow + 64), qf[2], c, 0, 0, 0);
    c = __builtin_amdgcn_mfma_i32_32x32x32_i8(*(const i32x4*)(krow + 96), qf[3], c, 0, 0, 0);
    float4 fk4[4];
#pragma unroll
    for (int g = 0; g < 4; ++g) fk4[g] = *(const float4*)&Fk[bhS + kb + g * 8 + 4 * hi];
    float p[16];
    const bool diag = (t == nt - 1);
#pragma unroll
    for (int r = 0; r < 16; ++r) {
      float v = (float)c[r] * fq * ((const float*)&fk4[r >> 2])[r & 3];
      if (diag && (kb + KR(r) > qcol)) v = NEG_INF_F;
      const float e = __expf(v - m);            // masked -> 0 exactly
      z += e;
      p[r] = rintf(127.0f * e);                 // 0..127 integer
    }
    // pack + lane-exchange into PV A-fragments (k-steps of 16)
#pragma unroll
    for (int s = 0; s < 2; ++s) {
      const int rs = s * 8;
      unsigned k0 = pkbf(p[rs + 0], p[rs + 1]);
      unsigned k1 = pkbf(p[rs + 2], p[rs + 3]);
      unsigned k2 = pkbf(p[rs + 4], p[rs + 5]);
      unsigned k3 = pkbf(p[rs + 6], p[rs + 7]);
      unsigned sx0 = __shfl_xor(k0, 32);
      unsigned sx1 = __shfl_xor(k1, 32);
      unsigned sx2 = __shfl_xor(k2, 32);
      unsigned sx3 = __shfl_xor(k3, 32);
      uint4 ww;
      ww.x = hi ? sx2 : k0;
      ww.y = hi ? sx3 : k1;
      ww.z = hi ? k2 : sx0;
      ww.w = hi ? k3 : sx1;
      const bf16x8 af = __builtin_bit_cast(bf16x8, ww);
      const int kg = kb + s * 16 + hi * 8;
#pragma unroll
      for (int dt = 0; dt < 4; ++dt) {
        const bf16x8 vf = *(const bf16x8*)(vdqt + ((size_t)bh * Dh + dt * 32 + l31) * Ss + kg);
        oacc[dt] = __builtin_amdgcn_mfma_f32_32x32x16_bf16(af, vf, oacc[dt], 0, 0, 0);
      }
    }
  }
  z += __shfl_xor(z, 32);
  if (lane < 32)
    s_osc[wid][l31] = (1.0f / z) / 127.0f / A2v[bhS + q0 + l31];
  __syncthreads();
  // O-frag: row q = q0 + KR(r), col d = dt*32 + l31
#pragma unroll
  for (int dt = 0; dt < 4; ++dt) {
#pragma unroll
    for (int r = 0; r < 16; ++r) {
      const int q = q0 + KR(r);
      oattn[((size_t)b * Ss + q) * Hid + h * Dh + dt * 32 + l31] = oacc[dt][r] * s_osc[wid][KR(r)];
    }
  }
}

extern "C" void kernel_launch(void* const* d_in, const int* in_sizes, int n_in,
                              void* d_out, int out_size, void* d_ws, size_t ws_size,
                              hipStream_t stream)
{
  const float* hidden = (const float*)d_in[0];
  const float* wq = (const float*)d_in[1];
  const float* wk = (const float*)d_in[2];
  const float* wv = (const float*)d_in[3];
  const float* wo = (const float*)d_in[4];
  float* out = (float*)d_out;

  char* p = (char*)d_ws;
  auto alloc = [&](size_t bytes) -> char* {
    char* r = p; p += (bytes + 255) & ~(size_t)255; return r;
  };
  int8_t* xq   = (int8_t*)alloc((size_t)Mr * Hid);
  int8_t* wbuf = (int8_t*)alloc((size_t)Hid * Hid);
  float*  projf= (float*) alloc((size_t)Bh * Ss * Dh * sizeof(float));
  int8_t* qqb  = (int8_t*)alloc((size_t)Bh * Ss * Dh);
  int8_t* kqb  = (int8_t*)alloc((size_t)Bh * Ss * Dh);
  bf16_t* vdqt = (bf16_t*)alloc((size_t)Bh * Dh * Ss * sizeof(bf16_t));
  float* sxa = (float*)alloc((size_t)Mr * sizeof(float));
  float* sw  = (float*)alloc((size_t)Hid * sizeof(float));
  float* Fq  = (float*)alloc((size_t)Bh * Ss * sizeof(float));
  float* Fk  = (float*)alloc((size_t)Bh * Ss * sizeof(float));
  float* A2v = (float*)alloc((size_t)Bh * Ss * sizeof(float));
  float* soa = (float*)alloc((size_t)Mr * sizeof(float));
  float* ctab = (float*)alloc((size_t)Ss * 64 * sizeof(float));
  float* stab = (float*)alloc((size_t)Ss * 64 * sizeof(float));
  float*  oat = projf;
  int8_t* oq  = xq;

  rope_table_kernel<<<Ss * 64 / 256, 256, 0, stream>>>(ctab, stab);
  quant_rows_kernel<<<Mr, 256, 0, stream>>>(hidden, xq, sxa, Hid, 127.f, -128.f, 127.f);

  dim3 gg(Mr / 128, Hid / 128);
  // Q
  quant_rows_kernel<<<Hid, 256, 0, stream>>>(wq, wbuf, sw, Hid, 7.f, -8.f, 7.f);
  gemm_kernel<<<gg, 256, 0, stream>>>(xq, sxa, wbuf, sw, projf, Mr, Hid, Hid, 1);
  rope_quant_kernel<<<Bh * Ss / 4, 256, 0, stream>>>(projf, ctab, stab, qqb, Fq);
  // K
  quant_rows_kernel<<<Hid, 256, 0, stream>>>(wk, wbuf, sw, Hid, 7.f, -8.f, 7.f);
  gemm_kernel<<<gg, 256, 0, stream>>>(xq, sxa, wbuf, sw, projf, Mr, Hid, Hid, 1);
  rope_quant_kernel<<<Bh * Ss / 4, 256, 0, stream>>>(projf, ctab, stab, kqb, Fk);
  // V
  quant_rows_kernel<<<Hid, 256, 0, stream>>>(wv, wbuf, sw, Hid, 7.f, -8.f, 7.f);
  gemm_kernel<<<gg, 256, 0, stream>>>(xq, sxa, wbuf, sw, projf, Mr, Hid, Hid, 1);
  vquant_kernel<<<Bh * 16, 256, 0, stream>>>(projf, vdqt, A2v);

  dim3 ga(Bh, Ss / 128);
  attn_kernel<<<ga, 256, 0, stream>>>(qqb, kqb, vdqt, Fq, Fk, A2v, oat);

  quant_rows_kernel<<<Mr, 256, 0, stream>>>(oat, oq, soa, Hid, 127.f, -128.f, 127.f);
  quant_rows_kernel<<<Hid, 256, 0, stream>>>(wo, wbuf, sw, Hid, 7.f, -8.f, 7.f);
  gemm_kernel<<<gg, 256, 0, stream>>>(oq, soa, wbuf, sw, out, Mr, Hid, Hid, 0);
}

// Round 7
// 446.920 us; speedup vs baseline: 1.2439x; 1.0516x over previous
//
#include <hip/hip_runtime.h>
#include <hip/hip_bf16.h>
#include <math.h>
#include <stdint.h>

#define NEG_INF_F (-3.4028234663852886e38f)

typedef __bf16 bf16_t;
typedef __bf16 bf16x8 __attribute__((ext_vector_type(8)));
typedef float f32x4 __attribute__((ext_vector_type(4)));
typedef float f32x16 __attribute__((ext_vector_type(16)));
typedef int i32x4 __attribute__((ext_vector_type(4)));
typedef int i32x16 __attribute__((ext_vector_type(16)));
typedef int8_t c8x4 __attribute__((ext_vector_type(4)));

static constexpr int Bb = 2, Ss = 1024, Hid = 4096, Nh = 32, Dh = 128;
static constexpr int Mr = Bb * Ss;   // 2048 token rows
static constexpr int Bh = Bb * Nh;   // 64 (batch*heads)

__device__ __forceinline__ void gload_lds16(const void* g, void* l) {
  __builtin_amdgcn_global_load_lds((const __attribute__((address_space(1))) void*)g,
                                   (__attribute__((address_space(3))) void*)l, 16, 0, 0);
}

__device__ __forceinline__ float wred_max(float v) {
#pragma unroll
  for (int off = 32; off > 0; off >>= 1) v = fmaxf(v, __shfl_xor(v, off));
  return v;
}

__device__ __forceinline__ unsigned pkbf(float a, float b) {
  unsigned short ua = __builtin_bit_cast(unsigned short, (bf16_t)a);
  unsigned short ub = __builtin_bit_cast(unsigned short, (bf16_t)b);
  return (unsigned)ua | ((unsigned)ub << 16);
}

// ---------------- RoPE cos/sin tables [S][64] ----------------
__global__ void rope_table_kernel(float* __restrict__ ctab, float* __restrict__ stab) {
  int i = blockIdx.x * 256 + threadIdx.x;   // 0 .. S*64-1
  int srow = i >> 6, d = i & 63;
  float invf = (float)pow(10000.0, -((double)(2 * d) / (double)Dh));
  float ang = (float)srow * invf;           // f32 mul like numpy outer()
  ctab[i] = (float)cos((double)ang);
  stab[i] = (float)sin((double)ang);
}

// ------------- per-row symmetric fake-quant: int8 codes + f32 scale -------------
__global__ __launch_bounds__(256) void quant_rows_kernel(
    const float* __restrict__ in, int8_t* __restrict__ outq,
    float* __restrict__ scale, int ncols, float qmax, float clo, float chi)
{
  const int row = blockIdx.x;
  const float* x = in + (size_t)row * ncols;
  int8_t* o = outq + (size_t)row * ncols;
  const int tid = threadIdx.x;
  const float4* x4 = (const float4*)x;
  const int n4 = ncols >> 2;
  float m = 0.f;
  for (int i = tid; i < n4; i += 256) {
    float4 v = x4[i];
    m = fmaxf(m, fmaxf(fmaxf(fabsf(v.x), fabsf(v.y)), fmaxf(fabsf(v.z), fabsf(v.w))));
  }
  m = wred_max(m);
  __shared__ float red[4];
  if ((tid & 63) == 0) red[tid >> 6] = m;
  __syncthreads();
  m = fmaxf(fmaxf(red[0], red[1]), fmaxf(red[2], red[3]));
  const float s = fmaxf(m / qmax, 1e-8f);
  if (tid == 0) scale[row] = s;
  c8x4* o4 = (c8x4*)o;
  for (int i = tid; i < n4; i += 256) {
    float4 v = x4[i];
    c8x4 r;
    r[0] = (int8_t)(int)fminf(fmaxf(rintf(v.x / s), clo), chi);
    r[1] = (int8_t)(int)fminf(fmaxf(rintf(v.y / s), clo), chi);
    r[2] = (int8_t)(int)fminf(fmaxf(rintf(v.z / s), clo), chi);
    r[3] = (int8_t)(int)fminf(fmaxf(rintf(v.w / s), clo), chi);
    o4[i] = r;
  }
}

// ------------- i8 GEMM: C[m,n] = (sum_k A[m,k]*W[n,k]) * sA[m] * sW[n] -------------
__global__ __launch_bounds__(256) void gemm_kernel(
    const int8_t* __restrict__ A, const float* __restrict__ sA,
    const int8_t* __restrict__ W, const float* __restrict__ sW,
    float* __restrict__ out, int M, int N, int K, int mode)
{
  __shared__ __align__(16) int8_t As[128 * 64];
  __shared__ __align__(16) int8_t Bs[128 * 64];
  const int tid = threadIdx.x, lane = tid & 63, wid = tid >> 6;
  const int bm = blockIdx.x * 128, bn = blockIdx.y * 128;
  const int wm = wid >> 1, wn = wid & 1;
  const int l15 = lane & 15, kg = lane >> 4;

  const int srow = wid * 16 + (lane >> 2);
  const int skin = (lane & 3) * 16;
  const int8_t* gA = A + (size_t)(bm + srow) * K + skin;
  const int8_t* gB = W + (size_t)(bn + srow) * K + skin;
  const size_t half = (size_t)64 * K;
  int8_t* lA = As + wid * 1024;   // wave-uniform base; HW adds lane*16B
  int8_t* lB = Bs + wid * 1024;

  i32x4 acc[4][4] = {};
  for (int k0 = 0; k0 < K; k0 += 64) {
    if (k0) __syncthreads();
    gload_lds16(gA + k0, lA);
    gload_lds16(gA + k0 + half, lA + 4096);
    gload_lds16(gB + k0, lB);
    gload_lds16(gB + k0 + half, lB + 4096);
    __syncthreads();
    i32x4 af[4], bw[4];
#pragma unroll
    for (int f = 0; f < 4; ++f) {
      af[f] = *(const i32x4*)&As[(wm * 64 + f * 16 + l15) * 64 + kg * 16];
      bw[f] = *(const i32x4*)&Bs[(wn * 64 + f * 16 + l15) * 64 + kg * 16];
    }
#pragma unroll
    for (int fm = 0; fm < 4; ++fm)
#pragma unroll
      for (int fn = 0; fn < 4; ++fn)
        acc[fm][fn] = __builtin_amdgcn_mfma_i32_16x16x64_i8(af[fm], bw[fn], acc[fm][fn], 0, 0, 0);
  }
#pragma unroll
  for (int fm = 0; fm < 4; ++fm) {
    const int row0 = bm + wm * 64 + fm * 16 + kg * 4;
#pragma unroll
    for (int fn = 0; fn < 4; ++fn) {
      const int col = bn + wn * 64 + fn * 16 + l15;
      const float swv = sW[col];
#pragma unroll
      for (int j = 0; j < 4; ++j) {
        const int row = row0 + j;
        const float val = (float)acc[fm][fn][j] * sA[row] * swv;
        size_t off;
        if (mode == 0) off = (size_t)row * N + col;
        else {
          int b = row >> 10, si = row & 1023, h = col >> 7, d = col & 127;
          off = (((size_t)(b * Nh + h)) * Ss + si) * Dh + d;
        }
        out[off] = val;
      }
    }
  }
}

// ------------- RoPE + per-row(D=128) quant for Q/K -------------
__global__ __launch_bounds__(256) void rope_quant_kernel(
    const float* __restrict__ xin,
    const float* __restrict__ ctab, const float* __restrict__ stab,
    int8_t* __restrict__ xq, float* __restrict__ F)
{
  const int gid = blockIdx.x * 4 + (threadIdx.x >> 6);
  const int lane = threadIdx.x & 63;
  const int srow = gid & (Ss - 1);
  const float* x = xin + (size_t)gid * Dh;
  const float xl = x[lane], xh = x[lane + 64];
  const float c = ctab[srow * 64 + lane], sn = stab[srow * 64 + lane];
  const float rl = __fsub_rn(__fmul_rn(xl, c), __fmul_rn(xh, sn));
  const float rh = __fadd_rn(__fmul_rn(xh, c), __fmul_rn(xl, sn));
  float ma = fmaxf(fabsf(rl), fabsf(rh));
  float n2 = rl * rl + rh * rh;
#pragma unroll
  for (int off = 32; off > 0; off >>= 1) {
    ma = fmaxf(ma, __shfl_xor(ma, off));
    n2 += __shfl_xor(n2, off);
  }
  const float s = fmaxf(ma / 127.0f, 1e-8f);
  const float ql = fminf(fmaxf(rintf(rl / s), -128.f), 127.f);
  const float qh = fminf(fmaxf(rintf(rh / s), -128.f), 127.f);
  float nq2 = ql * ql + qh * qh;
#pragma unroll
  for (int off = 32; off > 0; off >>= 1) nq2 += __shfl_xor(nq2, off);
  int8_t* o = xq + (size_t)gid * Dh;
  o[lane] = (int8_t)(int)ql;
  o[lane + 64] = (int8_t)(int)qh;
  if (lane == 0) F[gid] = sqrtf(n2 / nq2) * 0.2973017787506803f;  // 1/128^0.25
}

// ------------- V quant: dequant bf16 stored transposed [Bh][128][Ss] via LDS -------------
__global__ __launch_bounds__(256) void vquant_kernel(
    const float* __restrict__ vin, bf16_t* __restrict__ vdqt, float* __restrict__ a2v)
{
  __shared__ bf16_t s_v[128 * 66];
  const int tid = threadIdx.x, lane = tid & 63;
  const int l15 = lane & 15;
  const int qw = (tid >> 6) * 4 + (lane >> 4);
  const int bh = blockIdx.x >> 4;
  const int t0 = (blockIdx.x & 15) * 64;
  for (int it = 0; it < 4; ++it) {
    const int tt = qw * 4 + it;
    const size_t gid = (size_t)bh * Ss + t0 + tt;
    const float4 va = *(const float4*)(vin + gid * Dh + l15 * 8);
    const float4 vb = *(const float4*)(vin + gid * Dh + l15 * 8 + 4);
    float m = fmaxf(fmaxf(fmaxf(fabsf(va.x), fabsf(va.y)), fmaxf(fabsf(va.z), fabsf(va.w))),
                    fmaxf(fmaxf(fabsf(vb.x), fabsf(vb.y)), fmaxf(fabsf(vb.z), fabsf(vb.w))));
    float n2 = va.x * va.x + va.y * va.y + va.z * va.z + va.w * va.w +
               vb.x * vb.x + vb.y * vb.y + vb.z * vb.z + vb.w * vb.w;
#pragma unroll
    for (int off = 1; off < 16; off <<= 1) {
      m = fmaxf(m, __shfl_xor(m, off));
      n2 += __shfl_xor(n2, off);
    }
    const float s = fmaxf(m / 127.0f, 1e-8f);
    float q[8] = {va.x, va.y, va.z, va.w, vb.x, vb.y, vb.z, vb.w};
    float nq2 = 0.f;
#pragma unroll
    for (int e = 0; e < 8; ++e) {
      q[e] = fminf(fmaxf(rintf(q[e] / s), -128.f), 127.f);
      nq2 += q[e] * q[e];
      s_v[(l15 * 8 + e) * 66 + tt] = (bf16_t)(q[e] * s);
    }
#pragma unroll
    for (int off = 1; off < 16; off <<= 1) nq2 += __shfl_xor(nq2, off);
    if (l15 == 0) a2v[gid] = s * sqrtf(nq2) / sqrtf(n2);
  }
  __syncthreads();
  const int r = tid >> 1, hc = (tid & 1) * 32;
  const bf16_t* src = &s_v[r * 66 + hc];
  bf16_t* dst = vdqt + ((size_t)bh * Dh + r) * Ss + t0 + hc;
#pragma unroll
  for (int k = 0; k < 4; ++k) {
    bf16x8 t;
#pragma unroll
    for (int e = 0; e < 8; ++e) t[e] = src[k * 8 + e];
    *(bf16x8*)(dst + k * 8) = t;
  }
}

// ------------- fused attention: 1 wave per 32 q-rows, no LDS, no barriers -------------
// grid (Bh, 32); unit u = 31 - blockIdx.y (heavy-first); q0 = u*32; nt = u+1 k-tiles.
// Linear block id = bh + 64*y -> XCD = bh%8: each head's K/V stays on one XCD's L2.
// QK^T: mfma_i32_32x32x32_i8(A=K, B=Q) -> D[k][q], q = lane&31; dual accumulators.
// Pass A: row max. Pass B: recompute (bit-identical), exp, P codes packed bf16,
// shfl-exchange to PV A-frag, PV: mfma_f32_32x32x16_bf16(P, V^T). osc via shfl.
#define KR(r) (((r) & 3) + 8 * ((r) >> 2) + 4 * hi)
__global__ __launch_bounds__(64, 2) void attn_kernel(
    const int8_t* __restrict__ qq, const int8_t* __restrict__ kq,
    const bf16_t* __restrict__ vdqt,
    const float* __restrict__ Fq, const float* __restrict__ Fk,
    const float* __restrict__ A2v, float* __restrict__ oattn)
{
  const int bh = blockIdx.x, b = bh >> 5, h = bh & 31;
  const int lane = threadIdx.x & 63;
  const int l31 = lane & 31, hi = lane >> 5;
  const int u = 31 - (int)blockIdx.y;
  const int q0 = u * 32;
  const int nt = u + 1;
  const size_t bhS = (size_t)bh * Ss;

  // Q B-fragments (col = q = q0 + l31), 4 d-chunks of 32
  const int8_t* qrow = qq + (bhS + q0 + l31) * Dh + hi * 16;
  i32x4 qf[4];
#pragma unroll
  for (int c = 0; c < 4; ++c) qf[c] = *(const i32x4*)(qrow + c * 32);
  const float fq = Fq[bhS + q0 + l31];
  const int qcol = q0 + l31;

  // ---- pass A: row max (2-tile unroll, dual accumulators) ----
  float m = NEG_INF_F;
  int t = 0;
  for (; t + 1 < nt; t += 2) {
    const int kb0 = t * 32, kb1 = kb0 + 32;
    const int8_t* kr0 = kq + (bhS + kb0 + l31) * Dh + hi * 16;
    const int8_t* kr1 = kq + (bhS + kb1 + l31) * Dh + hi * 16;
    i32x16 ca = {}, cb = {}, da = {}, db = {};
    ca = __builtin_amdgcn_mfma_i32_32x32x32_i8(*(const i32x4*)(kr0),      qf[0], ca, 0, 0, 0);
    cb = __builtin_amdgcn_mfma_i32_32x32x32_i8(*(const i32x4*)(kr0 + 64), qf[2], cb, 0, 0, 0);
    da = __builtin_amdgcn_mfma_i32_32x32x32_i8(*(const i32x4*)(kr1),      qf[0], da, 0, 0, 0);
    db = __builtin_amdgcn_mfma_i32_32x32x32_i8(*(const i32x4*)(kr1 + 64), qf[2], db, 0, 0, 0);
    ca = __builtin_amdgcn_mfma_i32_32x32x32_i8(*(const i32x4*)(kr0 + 32), qf[1], ca, 0, 0, 0);
    cb = __builtin_amdgcn_mfma_i32_32x32x32_i8(*(const i32x4*)(kr0 + 96), qf[3], cb, 0, 0, 0);
    da = __builtin_amdgcn_mfma_i32_32x32x32_i8(*(const i32x4*)(kr1 + 32), qf[1], da, 0, 0, 0);
    db = __builtin_amdgcn_mfma_i32_32x32x32_i8(*(const i32x4*)(kr1 + 96), qf[3], db, 0, 0, 0);
    float4 fk40[4], fk41[4];
#pragma unroll
    for (int g = 0; g < 4; ++g) fk40[g] = *(const float4*)&Fk[bhS + kb0 + g * 8 + 4 * hi];
#pragma unroll
    for (int g = 0; g < 4; ++g) fk41[g] = *(const float4*)&Fk[bhS + kb1 + g * 8 + 4 * hi];
    const bool diag1 = (t + 1 == nt - 1);   // tile kb1 may touch the diagonal
#pragma unroll
    for (int r = 0; r < 16; ++r) {
      m = fmaxf(m, (float)(ca[r] + cb[r]) * fq * ((const float*)&fk40[r >> 2])[r & 3]);
      const float v1 = (float)(da[r] + db[r]) * fq * ((const float*)&fk41[r >> 2])[r & 3];
      if (!diag1 || (kb1 + KR(r) <= qcol)) m = fmaxf(m, v1);
    }
  }
  if (t < nt) {   // tail tile (always the diagonal when reached)
    const int kb = t * 32;
    const int8_t* krow = kq + (bhS + kb + l31) * Dh + hi * 16;
    i32x16 ca = {}, cb = {};
    ca = __builtin_amdgcn_mfma_i32_32x32x32_i8(*(const i32x4*)(krow),      qf[0], ca, 0, 0, 0);
    cb = __builtin_amdgcn_mfma_i32_32x32x32_i8(*(const i32x4*)(krow + 64), qf[2], cb, 0, 0, 0);
    ca = __builtin_amdgcn_mfma_i32_32x32x32_i8(*(const i32x4*)(krow + 32), qf[1], ca, 0, 0, 0);
    cb = __builtin_amdgcn_mfma_i32_32x32x32_i8(*(const i32x4*)(krow + 96), qf[3], cb, 0, 0, 0);
    float4 fk4[4];
#pragma unroll
    for (int g = 0; g < 4; ++g) fk4[g] = *(const float4*)&Fk[bhS + kb + g * 8 + 4 * hi];
#pragma unroll
    for (int r = 0; r < 16; ++r) {
      const float v = (float)(ca[r] + cb[r]) * fq * ((const float*)&fk4[r >> 2])[r & 3];
      if (kb + KR(r) <= qcol) m = fmaxf(m, v);
    }
  }
  m = fmaxf(m, __shfl_xor(m, 32));

  // ---- pass B: recompute + exp + P-codes -> PV (fused per tile) ----
  float z = 0.f;
  f32x16 oacc[4] = {};
  for (int tt = 0; tt < nt; ++tt) {
    const int kb = tt * 32;
    const int8_t* krow = kq + (bhS + kb + l31) * Dh + hi * 16;
    i32x16 ca = {}, cb = {};
    ca = __builtin_amdgcn_mfma_i32_32x32x32_i8(*(const i32x4*)(krow),      qf[0], ca, 0, 0, 0);
    cb = __builtin_amdgcn_mfma_i32_32x32x32_i8(*(const i32x4*)(krow + 64), qf[2], cb, 0, 0, 0);
    ca = __builtin_amdgcn_mfma_i32_32x32x32_i8(*(const i32x4*)(krow + 32), qf[1], ca, 0, 0, 0);
    cb = __builtin_amdgcn_mfma_i32_32x32x32_i8(*(const i32x4*)(krow + 96), qf[3], cb, 0, 0, 0);
    float4 fk4[4];
#pragma unroll
    for (int g = 0; g < 4; ++g) fk4[g] = *(const float4*)&Fk[bhS + kb + g * 8 + 4 * hi];
    float p[16];
    const bool diag = (tt == nt - 1);
#pragma unroll
    for (int r = 0; r < 16; ++r) {
      float v = (float)(ca[r] + cb[r]) * fq * ((const float*)&fk4[r >> 2])[r & 3];
      if (diag && (kb + KR(r) > qcol)) v = NEG_INF_F;
      const float e = __expf(v - m);            // masked -> 0 exactly
      z += e;
      p[r] = rintf(127.0f * e);                 // 0..127 integer
    }
    // pack + lane-exchange into PV A-fragments (k-steps of 16)
#pragma unroll
    for (int s = 0; s < 2; ++s) {
      const int rs = s * 8;
      unsigned k0 = pkbf(p[rs + 0], p[rs + 1]);
      unsigned k1 = pkbf(p[rs + 2], p[rs + 3]);
      unsigned k2 = pkbf(p[rs + 4], p[rs + 5]);
      unsigned k3 = pkbf(p[rs + 6], p[rs + 7]);
      unsigned sx0 = __shfl_xor(k0, 32);
      unsigned sx1 = __shfl_xor(k1, 32);
      unsigned sx2 = __shfl_xor(k2, 32);
      unsigned sx3 = __shfl_xor(k3, 32);
      uint4 ww;
      ww.x = hi ? sx2 : k0;
      ww.y = hi ? sx3 : k1;
      ww.z = hi ? k2 : sx0;
      ww.w = hi ? k3 : sx1;
      const bf16x8 af = __builtin_bit_cast(bf16x8, ww);
      const int kg = kb + s * 16 + hi * 8;
#pragma unroll
      for (int dt = 0; dt < 4; ++dt) {
        const bf16x8 vf = *(const bf16x8*)(vdqt + ((size_t)bh * Dh + dt * 32 + l31) * Ss + kg);
        oacc[dt] = __builtin_amdgcn_mfma_f32_32x32x16_bf16(af, vf, oacc[dt], 0, 0, 0);
      }
    }
  }
  z += __shfl_xor(z, 32);
  const float osc = (1.0f / z) / 127.0f / A2v[bhS + q0 + l31];
  // O-frag: row q = q0 + KR(r), col d = dt*32 + l31; per-row scale via shfl broadcast
#pragma unroll
  for (int dt = 0; dt < 4; ++dt) {
#pragma unroll
    for (int r = 0; r < 16; ++r) {
      const int q = q0 + KR(r);
      const float oscr = __shfl(osc, KR(r));
      oattn[((size_t)b * Ss + q) * Hid + h * Dh + dt * 32 + l31] = oacc[dt][r] * oscr;
    }
  }
}

extern "C" void kernel_launch(void* const* d_in, const int* in_sizes, int n_in,
                              void* d_out, int out_size, void* d_ws, size_t ws_size,
                              hipStream_t stream)
{
  const float* hidden = (const float*)d_in[0];
  const float* wq = (const float*)d_in[1];
  const float* wk = (const float*)d_in[2];
  const float* wv = (const float*)d_in[3];
  const float* wo = (const float*)d_in[4];
  float* out = (float*)d_out;

  char* p = (char*)d_ws;
  auto alloc = [&](size_t bytes) -> char* {
    char* r = p; p += (bytes + 255) & ~(size_t)255; return r;
  };
  int8_t* xq   = (int8_t*)alloc((size_t)Mr * Hid);
  int8_t* wbuf = (int8_t*)alloc((size_t)Hid * Hid);
  float*  projf= (float*) alloc((size_t)Bh * Ss * Dh * sizeof(float));
  int8_t* qqb  = (int8_t*)alloc((size_t)Bh * Ss * Dh);
  int8_t* kqb  = (int8_t*)alloc((size_t)Bh * Ss * Dh);
  bf16_t* vdqt = (bf16_t*)alloc((size_t)Bh * Dh * Ss * sizeof(bf16_t));
  float* sxa = (float*)alloc((size_t)Mr * sizeof(float));
  float* sw  = (float*)alloc((size_t)Hid * sizeof(float));
  float* Fq  = (float*)alloc((size_t)Bh * Ss * sizeof(float));
  float* Fk  = (float*)alloc((size_t)Bh * Ss * sizeof(float));
  float* A2v = (float*)alloc((size_t)Bh * Ss * sizeof(float));
  float* soa = (float*)alloc((size_t)Mr * sizeof(float));
  float* ctab = (float*)alloc((size_t)Ss * 64 * sizeof(float));
  float* stab = (float*)alloc((size_t)Ss * 64 * sizeof(float));
  float*  oat = projf;
  int8_t* oq  = xq;

  rope_table_kernel<<<Ss * 64 / 256, 256, 0, stream>>>(ctab, stab);
  quant_rows_kernel<<<Mr, 256, 0, stream>>>(hidden, xq, sxa, Hid, 127.f, -128.f, 127.f);

  dim3 gg(Mr / 128, Hid / 128);
  // Q
  quant_rows_kernel<<<Hid, 256, 0, stream>>>(wq, wbuf, sw, Hid, 7.f, -8.f, 7.f);
  gemm_kernel<<<gg, 256, 0, stream>>>(xq, sxa, wbuf, sw, projf, Mr, Hid, Hid, 1);
  rope_quant_kernel<<<Bh * Ss / 4, 256, 0, stream>>>(projf, ctab, stab, qqb, Fq);
  // K
  quant_rows_kernel<<<Hid, 256, 0, stream>>>(wk, wbuf, sw, Hid, 7.f, -8.f, 7.f);
  gemm_kernel<<<gg, 256, 0, stream>>>(xq, sxa, wbuf, sw, projf, Mr, Hid, Hid, 1);
  rope_quant_kernel<<<Bh * Ss / 4, 256, 0, stream>>>(projf, ctab, stab, kqb, Fk);
  // V
  quant_rows_kernel<<<Hid, 256, 0, stream>>>(wv, wbuf, sw, Hid, 7.f, -8.f, 7.f);
  gemm_kernel<<<gg, 256, 0, stream>>>(xq, sxa, wbuf, sw, projf, Mr, Hid, Hid, 1);
  vquant_kernel<<<Bh * 16, 256, 0, stream>>>(projf, vdqt, A2v);

  dim3 ga(Bh, 32);
  attn_kernel<<<ga, 64, 0, stream>>>(qqb, kqb, vdqt, Fq, Fk, A2v, oat);

  quant_rows_kernel<<<Mr, 256, 0, stream>>>(oat, oq, soa, Hid, 127.f, -128.f, 127.f);
  quant_rows_kernel<<<Hid, 256, 0, stream>>>(wo, wbuf, sw, Hid, 7.f, -8.f, 7.f);
  gemm_kernel<<<gg, 256, 0, stream>>>(oq, soa, wbuf, sw, out, Mr, Hid, Hid, 0);
}

// Round 8
// 411.210 us; speedup vs baseline: 1.3519x; 1.0868x over previous
//
#include <hip/hip_runtime.h>
#include <hip/hip_bf16.h>
#include <math.h>
#include <stdint.h>

#define NEG_INF_F (-3.4028234663852886e38f)

typedef __bf16 bf16_t;
typedef __bf16 bf16x8 __attribute__((ext_vector_type(8)));
typedef float f32x4 __attribute__((ext_vector_type(4)));
typedef float f32x16 __attribute__((ext_vector_type(16)));
typedef int i32x4 __attribute__((ext_vector_type(4)));
typedef int i32x16 __attribute__((ext_vector_type(16)));
typedef int8_t c8x4 __attribute__((ext_vector_type(4)));

static constexpr int Bb = 2, Ss = 1024, Hid = 4096, Nh = 32, Dh = 128;
static constexpr int Mr = Bb * Ss;   // 2048 token rows
static constexpr int Bh = Bb * Nh;   // 64 (batch*heads)

__device__ __forceinline__ void gload_lds16(const void* g, void* l) {
  __builtin_amdgcn_global_load_lds((const __attribute__((address_space(1))) void*)g,
                                   (__attribute__((address_space(3))) void*)l, 16, 0, 0);
}

__device__ __forceinline__ float wred_max(float v) {
#pragma unroll
  for (int off = 32; off > 0; off >>= 1) v = fmaxf(v, __shfl_xor(v, off));
  return v;
}

__device__ __forceinline__ unsigned pkbf(float a, float b) {
  unsigned short ua = __builtin_bit_cast(unsigned short, (bf16_t)a);
  unsigned short ub = __builtin_bit_cast(unsigned short, (bf16_t)b);
  return (unsigned)ua | ((unsigned)ub << 16);
}

// ---------------- RoPE cos/sin tables [S][64] ----------------
__global__ void rope_table_kernel(float* __restrict__ ctab, float* __restrict__ stab) {
  int i = blockIdx.x * 256 + threadIdx.x;   // 0 .. S*64-1
  int srow = i >> 6, d = i & 63;
  float invf = (float)pow(10000.0, -((double)(2 * d) / (double)Dh));
  float ang = (float)srow * invf;           // f32 mul like numpy outer()
  ctab[i] = (float)cos((double)ang);
  stab[i] = (float)sin((double)ang);
}

// ------------- per-row symmetric fake-quant: int8 codes + f32 scale -------------
__global__ __launch_bounds__(256) void quant_rows_kernel(
    const float* __restrict__ in, int8_t* __restrict__ outq,
    float* __restrict__ scale, int ncols, float qmax, float clo, float chi)
{
  const int row = blockIdx.x;
  const float* x = in + (size_t)row * ncols;
  int8_t* o = outq + (size_t)row * ncols;
  const int tid = threadIdx.x;
  const float4* x4 = (const float4*)x;
  const int n4 = ncols >> 2;
  float m = 0.f;
  for (int i = tid; i < n4; i += 256) {
    float4 v = x4[i];
    m = fmaxf(m, fmaxf(fmaxf(fabsf(v.x), fabsf(v.y)), fmaxf(fabsf(v.z), fabsf(v.w))));
  }
  m = wred_max(m);
  __shared__ float red[4];
  if ((tid & 63) == 0) red[tid >> 6] = m;
  __syncthreads();
  m = fmaxf(fmaxf(red[0], red[1]), fmaxf(red[2], red[3]));
  const float s = fmaxf(m / qmax, 1e-8f);
  if (tid == 0) scale[row] = s;
  c8x4* o4 = (c8x4*)o;
  for (int i = tid; i < n4; i += 256) {
    float4 v = x4[i];
    c8x4 r;
    r[0] = (int8_t)(int)fminf(fmaxf(rintf(v.x / s), clo), chi);
    r[1] = (int8_t)(int)fminf(fmaxf(rintf(v.y / s), clo), chi);
    r[2] = (int8_t)(int)fminf(fmaxf(rintf(v.z / s), clo), chi);
    r[3] = (int8_t)(int)fminf(fmaxf(rintf(v.w / s), clo), chi);
    o4[i] = r;
  }
}

// ------------- i8 GEMM with fused epilogues -------------
// MODE 0: plain f32 out[m*N+n]
// MODE 2: rope + per-(token,head) quant -> i8 codes [bh*Ss+s][128] + F factor
// MODE 3: per-(token,head) quant -> dequant bf16 TRANSPOSED [bh][d][Ss] + a2v
// LDS bank-conflict fix: linear LDS + pre-swizzled global source chunk
// (i&3)^((i>>3)&3), read chunk kg^((l15>>1)&3): 8-way -> 2-way (free).
// Wave mapping: rows wm*64 + fm*16 + kg*4 + j ; cols fn*32 + wn*16 + l15
// (interleaved cols put rope pairs (d, d+64) in the SAME LANE: fn and fn+2).
template <int MODE>
__global__ __launch_bounds__(256) void gemm_kernel(
    const int8_t* __restrict__ A, const float* __restrict__ sA,
    const int8_t* __restrict__ W, const float* __restrict__ sW,
    float* __restrict__ out0,
    int8_t* __restrict__ outq, float* __restrict__ Ff,
    bf16_t* __restrict__ vdq, float* __restrict__ a2vp,
    const float* __restrict__ ctab, const float* __restrict__ stab,
    int M, int N, int K)
{
  __shared__ __align__(16) int8_t As[128 * 64];
  __shared__ __align__(16) int8_t Bs[128 * 64];
  __shared__ float s_red[2][128][3];
  __shared__ __align__(16) char smem_vt[MODE == 3 ? (128 * 136 * 2) : 16];

  const int tid = threadIdx.x, lane = tid & 63, wid = tid >> 6;
  // XCD-aware bijective swizzle: 512 blocks, 8 XCDs, 4 n-panels per XCD.
  const int id = blockIdx.x;
  const int xcd = id & 7, within = id >> 3;
  const int nIdx = xcd * 4 + (within >> 4);
  const int mIdx = within & 15;
  const int bm = mIdx * 128, bn = nIdx * 128;

  const int wm = wid >> 1, wn = wid & 1;
  const int l15 = lane & 15, kg = lane >> 4;
  const int ckey = (l15 >> 1) & 3;

  // staging: lane i covers tile row r*64 + wid*16 + (i>>2), chunk (i&3); source
  // chunk pre-swizzled so swizzled read recovers linear data.
  const int srowL = wid * 16 + (lane >> 2);
  const int skin = ((lane & 3) ^ ((lane >> 3) & 3)) * 16;
  const int8_t* gA = A + (size_t)(bm + srowL) * K + skin;
  const int8_t* gB = W + (size_t)(bn + srowL) * K + skin;
  const size_t half = (size_t)64 * K;
  int8_t* lA = As + wid * 1024;
  int8_t* lB = Bs + wid * 1024;

  i32x4 acc[4][4] = {};
  for (int k0 = 0; k0 < K; k0 += 64) {
    if (k0) __syncthreads();
    gload_lds16(gA + k0, lA);
    gload_lds16(gA + k0 + half, lA + 4096);
    gload_lds16(gB + k0, lB);
    gload_lds16(gB + k0 + half, lB + 4096);
    __syncthreads();
    i32x4 af[4], bw[4];
#pragma unroll
    for (int f = 0; f < 4; ++f) {
      af[f] = *(const i32x4*)&As[(wm * 64 + f * 16 + l15) * 64 + (kg ^ ckey) * 16];
      bw[f] = *(const i32x4*)&Bs[(f * 32 + wn * 16 + l15) * 64 + (kg ^ ckey) * 16];
    }
#pragma unroll
    for (int fm = 0; fm < 4; ++fm)
#pragma unroll
      for (int fn = 0; fn < 4; ++fn)
        acc[fm][fn] = __builtin_amdgcn_mfma_i32_16x16x64_i8(af[fm], bw[fn], acc[fm][fn], 0, 0, 0);
  }

  // scales
  float sav[4][4], swv[4];
#pragma unroll
  for (int fm = 0; fm < 4; ++fm)
#pragma unroll
    for (int j = 0; j < 4; ++j) sav[fm][j] = sA[bm + wm * 64 + fm * 16 + kg * 4 + j];
#pragma unroll
  for (int fn = 0; fn < 4; ++fn) swv[fn] = sW[bn + fn * 32 + wn * 16 + l15];

  float val[4][4][4];
#pragma unroll
  for (int fm = 0; fm < 4; ++fm)
#pragma unroll
    for (int fn = 0; fn < 4; ++fn)
#pragma unroll
      for (int j = 0; j < 4; ++j)
        val[fm][fn][j] = (float)acc[fm][fn][j] * sav[fm][j] * swv[fn];

  if constexpr (MODE == 0) {
#pragma unroll
    for (int fm = 0; fm < 4; ++fm)
#pragma unroll
      for (int j = 0; j < 4; ++j) {
        const int row = bm + wm * 64 + fm * 16 + kg * 4 + j;
#pragma unroll
        for (int fn = 0; fn < 4; ++fn)
          out0[(size_t)row * N + bn + fn * 32 + wn * 16 + l15] = val[fm][fn][j];
      }
  } else {
    const int b = bm >> 10;
    const int bh = b * Nh + nIdx;   // head = nIdx (128 cols per head)
    float r_[4][4][4];
    if constexpr (MODE == 2) {
      const int dmA = wn * 16 + l15, dmB = 32 + wn * 16 + l15;
#pragma unroll
      for (int fm = 0; fm < 4; ++fm)
#pragma unroll
        for (int j = 0; j < 4; ++j) {
          const int srow = (bm + wm * 64 + fm * 16 + kg * 4 + j) & (Ss - 1);
          const float cA = ctab[srow * 64 + dmA], cB = ctab[srow * 64 + dmB];
          const float sA_ = stab[srow * 64 + dmA], sB_ = stab[srow * 64 + dmB];
          r_[fm][0][j] = __fsub_rn(__fmul_rn(val[fm][0][j], cA), __fmul_rn(val[fm][2][j], sA_));
          r_[fm][1][j] = __fsub_rn(__fmul_rn(val[fm][1][j], cB), __fmul_rn(val[fm][3][j], sB_));
          r_[fm][2][j] = __fadd_rn(__fmul_rn(val[fm][2][j], cA), __fmul_rn(val[fm][0][j], sA_));
          r_[fm][3][j] = __fadd_rn(__fmul_rn(val[fm][3][j], cB), __fmul_rn(val[fm][1][j], sB_));
        }
    } else {
#pragma unroll
      for (int fm = 0; fm < 4; ++fm)
#pragma unroll
        for (int fn = 0; fn < 4; ++fn)
#pragma unroll
          for (int j = 0; j < 4; ++j) r_[fm][fn][j] = val[fm][fn][j];
    }
    // round 1: this wave's 64-col partial (ma, n2) per row
    float ma_[4][4], n2_[4][4];
#pragma unroll
    for (int fm = 0; fm < 4; ++fm)
#pragma unroll
      for (int j = 0; j < 4; ++j) {
        float ma = 0.f, n2 = 0.f;
#pragma unroll
        for (int fn = 0; fn < 4; ++fn) {
          const float x = r_[fm][fn][j];
          ma = fmaxf(ma, fabsf(x));
          n2 += x * x;
        }
#pragma unroll
        for (int off = 1; off < 16; off <<= 1) {
          ma = fmaxf(ma, __shfl_xor(ma, off));
          n2 += __shfl_xor(n2, off);
        }
        ma_[fm][j] = ma;
        n2_[fm][j] = n2;
      }
    if (l15 == 0) {
#pragma unroll
      for (int fm = 0; fm < 4; ++fm)
#pragma unroll
        for (int j = 0; j < 4; ++j) {
          const int rl = wm * 64 + fm * 16 + kg * 4 + j;
          s_red[wn][rl][0] = ma_[fm][j];
          s_red[wn][rl][1] = n2_[fm][j];
        }
    }
    __syncthreads();
    float qc[4][4][4], svl[4][4], n2c[4][4], nq2_[4][4];
#pragma unroll
    for (int fm = 0; fm < 4; ++fm)
#pragma unroll
      for (int j = 0; j < 4; ++j) {
        const int rl = wm * 64 + fm * 16 + kg * 4 + j;
        const float ma = fmaxf(ma_[fm][j], s_red[wn ^ 1][rl][0]);
        const float n2 = n2_[fm][j] + s_red[wn ^ 1][rl][1];
        const float s = fmaxf(ma / 127.0f, 1e-8f);
        float nq2 = 0.f;
#pragma unroll
        for (int fn = 0; fn < 4; ++fn) {
          const float q = fminf(fmaxf(rintf(r_[fm][fn][j] / s), -128.f), 127.f);
          qc[fm][fn][j] = q;
          nq2 += q * q;
        }
#pragma unroll
        for (int off = 1; off < 16; off <<= 1) nq2 += __shfl_xor(nq2, off);
        svl[fm][j] = s;
        n2c[fm][j] = n2;
        nq2_[fm][j] = nq2;
      }
    if (l15 == 0) {
#pragma unroll
      for (int fm = 0; fm < 4; ++fm)
#pragma unroll
        for (int j = 0; j < 4; ++j)
          s_red[wn][wm * 64 + fm * 16 + kg * 4 + j][2] = nq2_[fm][j];
    }
    __syncthreads();

    if constexpr (MODE == 2) {
#pragma unroll
      for (int fm = 0; fm < 4; ++fm)
#pragma unroll
        for (int j = 0; j < 4; ++j) {
          const int rl = wm * 64 + fm * 16 + kg * 4 + j;
          const int stok = (bm + rl) & (Ss - 1);
          const size_t rowBase = ((size_t)bh * Ss + stok) * Dh;
#pragma unroll
          for (int fn = 0; fn < 4; ++fn)
            outq[rowBase + fn * 32 + wn * 16 + l15] = (int8_t)(int)qc[fm][fn][j];
          if (wn == 0 && l15 == 0) {
            const float nq2 = nq2_[fm][j] + s_red[1][rl][2];
            Ff[(size_t)bh * Ss + stok] = sqrtf(n2c[fm][j] / nq2) * 0.2973017787506803f;
          }
        }
    } else {   // MODE 3
      bf16_t* svt = (bf16_t*)smem_vt;
#pragma unroll
      for (int fm = 0; fm < 4; ++fm)
#pragma unroll
        for (int j = 0; j < 4; ++j) {
          const int t = wm * 64 + fm * 16 + kg * 4 + j;
#pragma unroll
          for (int fn = 0; fn < 4; ++fn) {
            const int d = fn * 32 + wn * 16 + l15;
            svt[d * 136 + t] = (bf16_t)(qc[fm][fn][j] * svl[fm][j]);
          }
          if (wn == 0 && l15 == 0) {
            const float nq2 = nq2_[fm][j] + s_red[1][t][2];
            a2vp[(size_t)bh * Ss + ((bm + t) & (Ss - 1))] =
                svl[fm][j] * sqrtf(nq2) / sqrtf(n2c[fm][j]);
          }
        }
      __syncthreads();
      // coalesced transposed store: vdq[bh][d][s0..s0+127]
      const int d = tid >> 1, toff = (tid & 1) * 64;
      const int s0 = bm & (Ss - 1);
      const bf16_t* src = svt + d * 136 + toff;
      bf16_t* dst = vdq + ((size_t)bh * Dh + d) * Ss + s0 + toff;
#pragma unroll
      for (int k = 0; k < 8; ++k) {
        bf16x8 tv;
#pragma unroll
        for (int e = 0; e < 8; ++e) tv[e] = src[k * 8 + e];
        *(bf16x8*)(dst + k * 8) = tv;
      }
    }
  }
}

// ------------- fused attention: 1 wave per 32 q-rows, no LDS, no barriers -------------
#define KR(r) (((r) & 3) + 8 * ((r) >> 2) + 4 * hi)
__global__ __launch_bounds__(64, 2) void attn_kernel(
    const int8_t* __restrict__ qq, const int8_t* __restrict__ kq,
    const bf16_t* __restrict__ vdqt,
    const float* __restrict__ Fq, const float* __restrict__ Fk,
    const float* __restrict__ A2v, float* __restrict__ oattn)
{
  const int bh = blockIdx.x, b = bh >> 5, h = bh & 31;
  const int lane = threadIdx.x & 63;
  const int l31 = lane & 31, hi = lane >> 5;
  const int u = 31 - (int)blockIdx.y;
  const int q0 = u * 32;
  const int nt = u + 1;
  const size_t bhS = (size_t)bh * Ss;

  const int8_t* qrow = qq + (bhS + q0 + l31) * Dh + hi * 16;
  i32x4 qf[4];
#pragma unroll
  for (int c = 0; c < 4; ++c) qf[c] = *(const i32x4*)(qrow + c * 32);
  const float fq = Fq[bhS + q0 + l31];
  const int qcol = q0 + l31;

  // ---- pass A: row max (2-tile unroll, dual accumulators) ----
  float m = NEG_INF_F;
  int t = 0;
  for (; t + 1 < nt; t += 2) {
    const int kb0 = t * 32, kb1 = kb0 + 32;
    const int8_t* kr0 = kq + (bhS + kb0 + l31) * Dh + hi * 16;
    const int8_t* kr1 = kq + (bhS + kb1 + l31) * Dh + hi * 16;
    i32x16 ca = {}, cb = {}, da = {}, db = {};
    ca = __builtin_amdgcn_mfma_i32_32x32x32_i8(*(const i32x4*)(kr0),      qf[0], ca, 0, 0, 0);
    cb = __builtin_amdgcn_mfma_i32_32x32x32_i8(*(const i32x4*)(kr0 + 64), qf[2], cb, 0, 0, 0);
    da = __builtin_amdgcn_mfma_i32_32x32x32_i8(*(const i32x4*)(kr1),      qf[0], da, 0, 0, 0);
    db = __builtin_amdgcn_mfma_i32_32x32x32_i8(*(const i32x4*)(kr1 + 64), qf[2], db, 0, 0, 0);
    ca = __builtin_amdgcn_mfma_i32_32x32x32_i8(*(const i32x4*)(kr0 + 32), qf[1], ca, 0, 0, 0);
    cb = __builtin_amdgcn_mfma_i32_32x32x32_i8(*(const i32x4*)(kr0 + 96), qf[3], cb, 0, 0, 0);
    da = __builtin_amdgcn_mfma_i32_32x32x32_i8(*(const i32x4*)(kr1 + 32), qf[1], da, 0, 0, 0);
    db = __builtin_amdgcn_mfma_i32_32x32x32_i8(*(const i32x4*)(kr1 + 96), qf[3], db, 0, 0, 0);
    float4 fk40[4], fk41[4];
#pragma unroll
    for (int g = 0; g < 4; ++g) fk40[g] = *(const float4*)&Fk[bhS + kb0 + g * 8 + 4 * hi];
#pragma unroll
    for (int g = 0; g < 4; ++g) fk41[g] = *(const float4*)&Fk[bhS + kb1 + g * 8 + 4 * hi];
    const bool diag1 = (t + 1 == nt - 1);
#pragma unroll
    for (int r = 0; r < 16; ++r) {
      m = fmaxf(m, (float)(ca[r] + cb[r]) * fq * ((const float*)&fk40[r >> 2])[r & 3]);
      const float v1 = (float)(da[r] + db[r]) * fq * ((const float*)&fk41[r >> 2])[r & 3];
      if (!diag1 || (kb1 + KR(r) <= qcol)) m = fmaxf(m, v1);
    }
  }
  if (t < nt) {
    const int kb = t * 32;
    const int8_t* krow = kq + (bhS + kb + l31) * Dh + hi * 16;
    i32x16 ca = {}, cb = {};
    ca = __builtin_amdgcn_mfma_i32_32x32x32_i8(*(const i32x4*)(krow),      qf[0], ca, 0, 0, 0);
    cb = __builtin_amdgcn_mfma_i32_32x32x32_i8(*(const i32x4*)(krow + 64), qf[2], cb, 0, 0, 0);
    ca = __builtin_amdgcn_mfma_i32_32x32x32_i8(*(const i32x4*)(krow + 32), qf[1], ca, 0, 0, 0);
    cb = __builtin_amdgcn_mfma_i32_32x32x32_i8(*(const i32x4*)(krow + 96), qf[3], cb, 0, 0, 0);
    float4 fk4[4];
#pragma unroll
    for (int g = 0; g < 4; ++g) fk4[g] = *(const float4*)&Fk[bhS + kb + g * 8 + 4 * hi];
#pragma unroll
    for (int r = 0; r < 16; ++r) {
      const float v = (float)(ca[r] + cb[r]) * fq * ((const float*)&fk4[r >> 2])[r & 3];
      if (kb + KR(r) <= qcol) m = fmaxf(m, v);
    }
  }
  m = fmaxf(m, __shfl_xor(m, 32));

  // ---- pass B: recompute + exp + P-codes -> PV ----
  float z = 0.f;
  f32x16 oacc[4] = {};
  for (int tt = 0; tt < nt; ++tt) {
    const int kb = tt * 32;
    const int8_t* krow = kq + (bhS + kb + l31) * Dh + hi * 16;
    i32x16 ca = {}, cb = {};
    ca = __builtin_amdgcn_mfma_i32_32x32x32_i8(*(const i32x4*)(krow),      qf[0], ca, 0, 0, 0);
    cb = __builtin_amdgcn_mfma_i32_32x32x32_i8(*(const i32x4*)(krow + 64), qf[2], cb, 0, 0, 0);
    ca = __builtin_amdgcn_mfma_i32_32x32x32_i8(*(const i32x4*)(krow + 32), qf[1], ca, 0, 0, 0);
    cb = __builtin_amdgcn_mfma_i32_32x32x32_i8(*(const i32x4*)(krow + 96), qf[3], cb, 0, 0, 0);
    float4 fk4[4];
#pragma unroll
    for (int g = 0; g < 4; ++g) fk4[g] = *(const float4*)&Fk[bhS + kb + g * 8 + 4 * hi];
    float p[16];
    const bool diag = (tt == nt - 1);
#pragma unroll
    for (int r = 0; r < 16; ++r) {
      float v = (float)(ca[r] + cb[r]) * fq * ((const float*)&fk4[r >> 2])[r & 3];
      if (diag && (kb + KR(r) > qcol)) v = NEG_INF_F;
      const float e = __expf(v - m);
      z += e;
      p[r] = rintf(127.0f * e);
    }
#pragma unroll
    for (int s = 0; s < 2; ++s) {
      const int rs = s * 8;
      unsigned k0 = pkbf(p[rs + 0], p[rs + 1]);
      unsigned k1 = pkbf(p[rs + 2], p[rs + 3]);
      unsigned k2 = pkbf(p[rs + 4], p[rs + 5]);
      unsigned k3 = pkbf(p[rs + 6], p[rs + 7]);
      unsigned sx0 = __shfl_xor(k0, 32);
      unsigned sx1 = __shfl_xor(k1, 32);
      unsigned sx2 = __shfl_xor(k2, 32);
      unsigned sx3 = __shfl_xor(k3, 32);
      uint4 ww;
      ww.x = hi ? sx2 : k0;
      ww.y = hi ? sx3 : k1;
      ww.z = hi ? k2 : sx0;
      ww.w = hi ? k3 : sx1;
      const bf16x8 af = __builtin_bit_cast(bf16x8, ww);
      const int kg2 = kb + s * 16 + hi * 8;
#pragma unroll
      for (int dt = 0; dt < 4; ++dt) {
        const bf16x8 vf = *(const bf16x8*)(vdqt + ((size_t)bh * Dh + dt * 32 + l31) * Ss + kg2);
        oacc[dt] = __builtin_amdgcn_mfma_f32_32x32x16_bf16(af, vf, oacc[dt], 0, 0, 0);
      }
    }
  }
  z += __shfl_xor(z, 32);
  const float osc = (1.0f / z) / 127.0f / A2v[bhS + q0 + l31];
#pragma unroll
  for (int dt = 0; dt < 4; ++dt) {
#pragma unroll
    for (int r = 0; r < 16; ++r) {
      const int q = q0 + KR(r);
      const float oscr = __shfl(osc, KR(r));
      oattn[((size_t)b * Ss + q) * Hid + h * Dh + dt * 32 + l31] = oacc[dt][r] * oscr;
    }
  }
}

extern "C" void kernel_launch(void* const* d_in, const int* in_sizes, int n_in,
                              void* d_out, int out_size, void* d_ws, size_t ws_size,
                              hipStream_t stream)
{
  const float* hidden = (const float*)d_in[0];
  const float* wq = (const float*)d_in[1];
  const float* wk = (const float*)d_in[2];
  const float* wv = (const float*)d_in[3];
  const float* wo = (const float*)d_in[4];
  float* out = (float*)d_out;

  char* p = (char*)d_ws;
  auto alloc = [&](size_t bytes) -> char* {
    char* r = p; p += (bytes + 255) & ~(size_t)255; return r;
  };
  int8_t* xq   = (int8_t*)alloc((size_t)Mr * Hid);
  int8_t* wbuf = (int8_t*)alloc((size_t)Hid * Hid);
  float*  oat  = (float*) alloc((size_t)Bh * Ss * Dh * sizeof(float));
  int8_t* qqb  = (int8_t*)alloc((size_t)Bh * Ss * Dh);
  int8_t* kqb  = (int8_t*)alloc((size_t)Bh * Ss * Dh);
  bf16_t* vdqt = (bf16_t*)alloc((size_t)Bh * Dh * Ss * sizeof(bf16_t));
  float* sxa = (float*)alloc((size_t)Mr * sizeof(float));
  float* sw  = (float*)alloc((size_t)Hid * sizeof(float));
  float* Fq  = (float*)alloc((size_t)Bh * Ss * sizeof(float));
  float* Fk  = (float*)alloc((size_t)Bh * Ss * sizeof(float));
  float* A2v = (float*)alloc((size_t)Bh * Ss * sizeof(float));
  float* soa = (float*)alloc((size_t)Mr * sizeof(float));
  float* ctab = (float*)alloc((size_t)Ss * 64 * sizeof(float));
  float* stab = (float*)alloc((size_t)Ss * 64 * sizeof(float));
  int8_t* oq  = xq;   // xq dead after the three projections

  rope_table_kernel<<<Ss * 64 / 256, 256, 0, stream>>>(ctab, stab);
  quant_rows_kernel<<<Mr, 256, 0, stream>>>(hidden, xq, sxa, Hid, 127.f, -128.f, 127.f);

  // Q
  quant_rows_kernel<<<Hid, 256, 0, stream>>>(wq, wbuf, sw, Hid, 7.f, -8.f, 7.f);
  gemm_kernel<2><<<512, 256, 0, stream>>>(xq, sxa, wbuf, sw, nullptr, qqb, Fq,
                                          nullptr, nullptr, ctab, stab, Mr, Hid, Hid);
  // K
  quant_rows_kernel<<<Hid, 256, 0, stream>>>(wk, wbuf, sw, Hid, 7.f, -8.f, 7.f);
  gemm_kernel<2><<<512, 256, 0, stream>>>(xq, sxa, wbuf, sw, nullptr, kqb, Fk,
                                          nullptr, nullptr, ctab, stab, Mr, Hid, Hid);
  // V
  quant_rows_kernel<<<Hid, 256, 0, stream>>>(wv, wbuf, sw, Hid, 7.f, -8.f, 7.f);
  gemm_kernel<3><<<512, 256, 0, stream>>>(xq, sxa, wbuf, sw, nullptr, nullptr, nullptr,
                                          vdqt, A2v, ctab, stab, Mr, Hid, Hid);

  dim3 ga(Bh, 32);
  attn_kernel<<<ga, 64, 0, stream>>>(qqb, kqb, vdqt, Fq, Fk, A2v, oat);

  quant_rows_kernel<<<Mr, 256, 0, stream>>>(oat, oq, soa, Hid, 127.f, -128.f, 127.f);
  quant_rows_kernel<<<Hid, 256, 0, stream>>>(wo, wbuf, sw, Hid, 7.f, -8.f, 7.f);
  gemm_kernel<0><<<512, 256, 0, stream>>>(oq, soa, wbuf, sw, out, nullptr, nullptr,
                                          nullptr, nullptr, nullptr, nullptr, Mr, Hid, Hid);
}

// Round 9
// 365.779 us; speedup vs baseline: 1.5198x; 1.1242x over previous
//
#include <hip/hip_runtime.h>
#include <hip/hip_bf16.h>
#include <math.h>
#include <stdint.h>

#define NEG_INF_F (-3.4028234663852886e38f)

typedef __bf16 bf16_t;
typedef __bf16 bf16x8 __attribute__((ext_vector_type(8)));
typedef float f32x4 __attribute__((ext_vector_type(4)));
typedef float f32x16 __attribute__((ext_vector_type(16)));
typedef int i32x4 __attribute__((ext_vector_type(4)));
typedef int i32x16 __attribute__((ext_vector_type(16)));
typedef int8_t c8x4 __attribute__((ext_vector_type(4)));

static constexpr int Bb = 2, Ss = 1024, Hid = 4096, Nh = 32, Dh = 128;
static constexpr int Mr = Bb * Ss;   // 2048 token rows
static constexpr int Bh = Bb * Nh;   // 64 (batch*heads)

__device__ __forceinline__ void gload_lds16(const void* g, void* l) {
  __builtin_amdgcn_global_load_lds((const __attribute__((address_space(1))) void*)g,
                                   (__attribute__((address_space(3))) void*)l, 16, 0, 0);
}

__device__ __forceinline__ float wred_max(float v) {
#pragma unroll
  for (int off = 32; off > 0; off >>= 1) v = fmaxf(v, __shfl_xor(v, off));
  return v;
}

__device__ __forceinline__ unsigned pkbf(float a, float b) {
  unsigned short ua = __builtin_bit_cast(unsigned short, (bf16_t)a);
  unsigned short ub = __builtin_bit_cast(unsigned short, (bf16_t)b);
  return (unsigned)ua | ((unsigned)ub << 16);
}

// ---------------- RoPE cos/sin tables [S][64] ----------------
__global__ void rope_table_kernel(float* __restrict__ ctab, float* __restrict__ stab) {
  int i = blockIdx.x * 256 + threadIdx.x;   // 0 .. S*64-1
  int srow = i >> 6, d = i & 63;
  float invf = (float)pow(10000.0, -((double)(2 * d) / (double)Dh));
  float ang = (float)srow * invf;           // f32 mul like numpy outer()
  ctab[i] = (float)cos((double)ang);
  stab[i] = (float)sin((double)ang);
}

// ------------- per-row symmetric fake-quant: int8 codes + f32 scale -------------
__device__ __forceinline__ void quant_row_body(
    const float* __restrict__ x, int8_t* __restrict__ o, float* __restrict__ scale,
    int row, int ncols, float qmax, float clo, float chi)
{
  const int tid = threadIdx.x;
  const float4* x4 = (const float4*)x;
  const int n4 = ncols >> 2;
  float m = 0.f;
  for (int i = tid; i < n4; i += 256) {
    float4 v = x4[i];
    m = fmaxf(m, fmaxf(fmaxf(fabsf(v.x), fabsf(v.y)), fmaxf(fabsf(v.z), fabsf(v.w))));
  }
  m = wred_max(m);
  __shared__ float red[4];
  if ((tid & 63) == 0) red[tid >> 6] = m;
  __syncthreads();
  m = fmaxf(fmaxf(red[0], red[1]), fmaxf(red[2], red[3]));
  const float s = fmaxf(m / qmax, 1e-8f);
  if (tid == 0) scale[row] = s;
  c8x4* o4 = (c8x4*)o;
  for (int i = tid; i < n4; i += 256) {
    float4 v = x4[i];
    c8x4 r;
    r[0] = (int8_t)(int)fminf(fmaxf(rintf(v.x / s), clo), chi);
    r[1] = (int8_t)(int)fminf(fmaxf(rintf(v.y / s), clo), chi);
    r[2] = (int8_t)(int)fminf(fmaxf(rintf(v.z / s), clo), chi);
    r[3] = (int8_t)(int)fminf(fmaxf(rintf(v.w / s), clo), chi);
    o4[i] = r;
  }
}

__global__ __launch_bounds__(256) void quant_rows_kernel(
    const float* __restrict__ in, int8_t* __restrict__ outq,
    float* __restrict__ scale, int ncols, float qmax, float clo, float chi)
{
  const int row = blockIdx.x;
  quant_row_body(in + (size_t)row * ncols, outq + (size_t)row * ncols, scale,
                 row, ncols, qmax, clo, chi);
}

// 3 weights in one launch (w4 quant): sel = id>>12, row = id&4095
__global__ __launch_bounds__(256) void quant_w3_kernel(
    const float* __restrict__ w0, const float* __restrict__ w1, const float* __restrict__ w2,
    int8_t* __restrict__ o0, int8_t* __restrict__ o1, int8_t* __restrict__ o2,
    float* __restrict__ s0, float* __restrict__ s1, float* __restrict__ s2)
{
  const int sel = blockIdx.x >> 12, row = blockIdx.x & 4095;
  const float* in = sel == 0 ? w0 : (sel == 1 ? w1 : w2);
  int8_t* o = sel == 0 ? o0 : (sel == 1 ? o1 : o2);
  float* sc = sel == 0 ? s0 : (sel == 1 ? s1 : s2);
  quant_row_body(in + (size_t)row * Hid, o + (size_t)row * Hid, sc, row, Hid,
                 7.f, -8.f, 7.f);
}

// ================= fused QKV i8 GEMM, BK=128, epilogue per weight =================
// grid 1536; nIdx 0..95: wsel = nIdx>>5 (0:Q 1:K 2:V), head = nIdx&31.
// rows: bm + wm*64 + fm*16 + kg4*4 + j ; cols: bn + fn*32 + wn*16 + l15.
// LDS: [0,34816) As(16K)+Bs(16K) during K-loop, reused as V-transpose; s_red after.
// Bank swizzle (128B rows): slot(row,c) holds global chunk c^(row&7);
// source chunk (lane&7)^(lane>>3); read chunk (g*4+kg4)^(l15&7) -> 2-way (free).
__global__ __launch_bounds__(256) void qkv_gemm_kernel(
    const int8_t* __restrict__ A, const float* __restrict__ sA,
    const int8_t* __restrict__ wqz, const int8_t* __restrict__ wkz, const int8_t* __restrict__ wvz,
    const float* __restrict__ swq, const float* __restrict__ swk, const float* __restrict__ swv,
    int8_t* __restrict__ qqb, float* __restrict__ Fq,
    int8_t* __restrict__ kqb, float* __restrict__ Fk,
    bf16_t* __restrict__ vdq, float* __restrict__ a2vp,
    const float* __restrict__ ctab, const float* __restrict__ stab)
{
  __shared__ __align__(16) char smem[34816 + 3072];
  int8_t* As = (int8_t*)smem;
  int8_t* Bs = (int8_t*)(smem + 16384);
  float (*s_red)[128][3] = (float (*)[128][3])(smem + 34816);

  const int tid = threadIdx.x, lane = tid & 63, wid = tid >> 6;
  const int id = blockIdx.x;                 // 1536 blocks, 8 XCDs, 12 n-panels each
  const int xcd = id & 7, within = id >> 3;  // within 0..191
  const int nIdx = xcd * 12 + (within >> 4); // 0..95
  const int mIdx = within & 15;
  const int wsel = nIdx >> 5, head = nIdx & 31;
  const int bm = mIdx * 128, bn = head * 128;
  const int8_t* W = wsel == 0 ? wqz : (wsel == 1 ? wkz : wvz);
  const float* sW = wsel == 0 ? swq : (wsel == 1 ? swk : swv);
  constexpr int K = Hid;

  const int wm = wid >> 1, wn = wid & 1;
  const int l15 = lane & 15, kg4 = lane >> 4;

  const int strow = wid * 8 + (lane >> 3);
  const int schunk = ((lane & 7) ^ (lane >> 3)) * 16;
  const int8_t* gA = A + (size_t)(bm + strow) * K + schunk;
  const int8_t* gB = W + (size_t)(bn + strow) * K + schunk;

  i32x4 acc[4][4] = {};
  for (int k0 = 0; k0 < K; k0 += 128) {
    if (k0) __syncthreads();
#pragma unroll
    for (int r = 0; r < 4; ++r) {
      gload_lds16(gA + k0 + (size_t)r * 32 * K, As + r * 4096 + wid * 1024);
      gload_lds16(gB + k0 + (size_t)r * 32 * K, Bs + r * 4096 + wid * 1024);
    }
    __syncthreads();
#pragma unroll
    for (int g = 0; g < 2; ++g) {
      i32x4 af[4], bw[4];
#pragma unroll
      for (int f = 0; f < 4; ++f) {
        const int ca = (((g << 2) | kg4) ^ (l15 & 7)) * 16;
        af[f] = *(const i32x4*)&As[(wm * 64 + f * 16 + l15) * 128 + ca];
        bw[f] = *(const i32x4*)&Bs[(f * 32 + wn * 16 + l15) * 128 + ca];
      }
#pragma unroll
      for (int fm = 0; fm < 4; ++fm)
#pragma unroll
        for (int fn = 0; fn < 4; ++fn)
          acc[fm][fn] = __builtin_amdgcn_mfma_i32_16x16x64_i8(af[fm], bw[fn], acc[fm][fn], 0, 0, 0);
    }
  }

  float sav[4][4], swv_[4];
#pragma unroll
  for (int fm = 0; fm < 4; ++fm)
#pragma unroll
    for (int j = 0; j < 4; ++j) sav[fm][j] = sA[bm + wm * 64 + fm * 16 + kg4 * 4 + j];
#pragma unroll
  for (int fn = 0; fn < 4; ++fn) swv_[fn] = sW[bn + fn * 32 + wn * 16 + l15];

  float val[4][4][4];
#pragma unroll
  for (int fm = 0; fm < 4; ++fm)
#pragma unroll
    for (int fn = 0; fn < 4; ++fn)
#pragma unroll
      for (int j = 0; j < 4; ++j)
        val[fm][fn][j] = (float)acc[fm][fn][j] * sav[fm][j] * swv_[fn];

  const int b = bm >> 10;
  const int bh = b * Nh + head;
  float r_[4][4][4];
  if (wsel != 2) {   // Q or K: rope
    const int dmA = wn * 16 + l15, dmB = 32 + wn * 16 + l15;
#pragma unroll
    for (int fm = 0; fm < 4; ++fm)
#pragma unroll
      for (int j = 0; j < 4; ++j) {
        const int srow = (bm + wm * 64 + fm * 16 + kg4 * 4 + j) & (Ss - 1);
        const float cA = ctab[srow * 64 + dmA], cB = ctab[srow * 64 + dmB];
        const float sA_ = stab[srow * 64 + dmA], sB_ = stab[srow * 64 + dmB];
        r_[fm][0][j] = __fsub_rn(__fmul_rn(val[fm][0][j], cA), __fmul_rn(val[fm][2][j], sA_));
        r_[fm][1][j] = __fsub_rn(__fmul_rn(val[fm][1][j], cB), __fmul_rn(val[fm][3][j], sB_));
        r_[fm][2][j] = __fadd_rn(__fmul_rn(val[fm][2][j], cA), __fmul_rn(val[fm][0][j], sA_));
        r_[fm][3][j] = __fadd_rn(__fmul_rn(val[fm][3][j], cB), __fmul_rn(val[fm][1][j], sB_));
      }
  } else {
#pragma unroll
    for (int fm = 0; fm < 4; ++fm)
#pragma unroll
      for (int fn = 0; fn < 4; ++fn)
#pragma unroll
        for (int j = 0; j < 4; ++j) r_[fm][fn][j] = val[fm][fn][j];
  }
  // per-row (ma, n2): wave-half partial then cross-wn via s_red
  float ma_[4][4], n2_[4][4];
#pragma unroll
  for (int fm = 0; fm < 4; ++fm)
#pragma unroll
    for (int j = 0; j < 4; ++j) {
      float ma = 0.f, n2 = 0.f;
#pragma unroll
      for (int fn = 0; fn < 4; ++fn) {
        const float x = r_[fm][fn][j];
        ma = fmaxf(ma, fabsf(x));
        n2 += x * x;
      }
#pragma unroll
      for (int off = 1; off < 16; off <<= 1) {
        ma = fmaxf(ma, __shfl_xor(ma, off));
        n2 += __shfl_xor(n2, off);
      }
      ma_[fm][j] = ma;
      n2_[fm][j] = n2;
    }
  if (l15 == 0) {
#pragma unroll
    for (int fm = 0; fm < 4; ++fm)
#pragma unroll
      for (int j = 0; j < 4; ++j) {
        const int rl = wm * 64 + fm * 16 + kg4 * 4 + j;
        s_red[wn][rl][0] = ma_[fm][j];
        s_red[wn][rl][1] = n2_[fm][j];
      }
  }
  __syncthreads();   // also retires As/Bs for the vt reuse below
  float qc[4][4][4], svl[4][4], n2c[4][4], nq2_[4][4];
#pragma unroll
  for (int fm = 0; fm < 4; ++fm)
#pragma unroll
    for (int j = 0; j < 4; ++j) {
      const int rl = wm * 64 + fm * 16 + kg4 * 4 + j;
      const float ma = fmaxf(ma_[fm][j], s_red[wn ^ 1][rl][0]);
      const float n2 = n2_[fm][j] + s_red[wn ^ 1][rl][1];
      const float s = fmaxf(ma / 127.0f, 1e-8f);
      float nq2 = 0.f;
#pragma unroll
      for (int fn = 0; fn < 4; ++fn) {
        const float q = fminf(fmaxf(rintf(r_[fm][fn][j] / s), -128.f), 127.f);
        qc[fm][fn][j] = q;
        nq2 += q * q;
      }
#pragma unroll
      for (int off = 1; off < 16; off <<= 1) nq2 += __shfl_xor(nq2, off);
      svl[fm][j] = s;
      n2c[fm][j] = n2;
      nq2_[fm][j] = nq2;
    }
  __syncthreads();   // s_red[ ][ ][0..1] reads done before slot 2 overwrite ordering
  if (l15 == 0) {
#pragma unroll
    for (int fm = 0; fm < 4; ++fm)
#pragma unroll
      for (int j = 0; j < 4; ++j)
        s_red[wn][wm * 64 + fm * 16 + kg4 * 4 + j][2] = nq2_[fm][j];
  }
  __syncthreads();

  if (wsel != 2) {
    int8_t* outq = (wsel == 0) ? qqb : kqb;
    float* Ff = (wsel == 0) ? Fq : Fk;
#pragma unroll
    for (int fm = 0; fm < 4; ++fm)
#pragma unroll
      for (int j = 0; j < 4; ++j) {
        const int rl = wm * 64 + fm * 16 + kg4 * 4 + j;
        const int stok = (bm + rl) & (Ss - 1);
        const size_t rowBase = ((size_t)bh * Ss + stok) * Dh;
#pragma unroll
        for (int fn = 0; fn < 4; ++fn)
          outq[rowBase + fn * 32 + wn * 16 + l15] = (int8_t)(int)qc[fm][fn][j];
        if (wn == 0 && l15 == 0) {
          const float nq2 = nq2_[fm][j] + s_red[1][rl][2];
          Ff[(size_t)bh * Ss + stok] = sqrtf(n2c[fm][j] / nq2) * 0.2973017787506803f;
        }
      }
  } else {
    bf16_t* svt = (bf16_t*)smem;   // reuses As/Bs region (retired above)
#pragma unroll
    for (int fm = 0; fm < 4; ++fm)
#pragma unroll
      for (int j = 0; j < 4; ++j) {
        const int t = wm * 64 + fm * 16 + kg4 * 4 + j;
#pragma unroll
        for (int fn = 0; fn < 4; ++fn) {
          const int d = fn * 32 + wn * 16 + l15;
          svt[d * 136 + t] = (bf16_t)(qc[fm][fn][j] * svl[fm][j]);
        }
        if (wn == 0 && l15 == 0) {
          const float nq2 = nq2_[fm][j] + s_red[1][t][2];
          a2vp[(size_t)bh * Ss + ((bm + t) & (Ss - 1))] =
              svl[fm][j] * sqrtf(nq2) / sqrtf(n2c[fm][j]);
        }
      }
    __syncthreads();
    const int d = tid >> 1, toff = (tid & 1) * 64;
    const int s0 = bm & (Ss - 1);
    const bf16_t* src = svt + d * 136 + toff;
    bf16_t* dst = vdq + ((size_t)bh * Dh + d) * Ss + s0 + toff;
#pragma unroll
    for (int k = 0; k < 8; ++k) {
      bf16x8 tv;
#pragma unroll
      for (int e = 0; e < 8; ++e) tv[e] = src[k * 8 + e];
      *(bf16x8*)(dst + k * 8) = tv;
    }
  }
}

// ================= output i8 GEMM (plain f32 store), BK=128 =================
__global__ __launch_bounds__(256) void gemm0_kernel(
    const int8_t* __restrict__ A, const float* __restrict__ sA,
    const int8_t* __restrict__ W, const float* __restrict__ sW,
    float* __restrict__ out, int M, int N, int K)
{
  __shared__ __align__(16) int8_t As[128 * 128];
  __shared__ __align__(16) int8_t Bs[128 * 128];
  const int tid = threadIdx.x, lane = tid & 63, wid = tid >> 6;
  const int id = blockIdx.x;
  const int xcd = id & 7, within = id >> 3;
  const int nIdx = xcd * 4 + (within >> 4);
  const int mIdx = within & 15;
  const int bm = mIdx * 128, bn = nIdx * 128;
  const int wm = wid >> 1, wn = wid & 1;
  const int l15 = lane & 15, kg4 = lane >> 4;

  const int strow = wid * 8 + (lane >> 3);
  const int schunk = ((lane & 7) ^ (lane >> 3)) * 16;
  const int8_t* gA = A + (size_t)(bm + strow) * K + schunk;
  const int8_t* gB = W + (size_t)(bn + strow) * K + schunk;

  i32x4 acc[4][4] = {};
  for (int k0 = 0; k0 < K; k0 += 128) {
    if (k0) __syncthreads();
#pragma unroll
    for (int r = 0; r < 4; ++r) {
      gload_lds16(gA + k0 + (size_t)r * 32 * K, As + r * 4096 + wid * 1024);
      gload_lds16(gB + k0 + (size_t)r * 32 * K, Bs + r * 4096 + wid * 1024);
    }
    __syncthreads();
#pragma unroll
    for (int g = 0; g < 2; ++g) {
      i32x4 af[4], bw[4];
#pragma unroll
      for (int f = 0; f < 4; ++f) {
        const int ca = (((g << 2) | kg4) ^ (l15 & 7)) * 16;
        af[f] = *(const i32x4*)&As[(wm * 64 + f * 16 + l15) * 128 + ca];
        bw[f] = *(const i32x4*)&Bs[(f * 32 + wn * 16 + l15) * 128 + ca];
      }
#pragma unroll
      for (int fm = 0; fm < 4; ++fm)
#pragma unroll
        for (int fn = 0; fn < 4; ++fn)
          acc[fm][fn] = __builtin_amdgcn_mfma_i32_16x16x64_i8(af[fm], bw[fn], acc[fm][fn], 0, 0, 0);
    }
  }
#pragma unroll
  for (int fm = 0; fm < 4; ++fm) {
#pragma unroll
    for (int j = 0; j < 4; ++j) {
      const int row = bm + wm * 64 + fm * 16 + kg4 * 4 + j;
      const float sa = sA[row];
#pragma unroll
      for (int fn = 0; fn < 4; ++fn) {
        const int col = bn + fn * 32 + wn * 16 + l15;
        out[(size_t)row * N + col] = (float)acc[fm][fn][j] * sa * sW[col];
      }
    }
  }
}

// ------------- fused attention: 1 wave per 32 q-rows, no LDS, no barriers -------------
#define KR(r) (((r) & 3) + 8 * ((r) >> 2) + 4 * hi)
__global__ __launch_bounds__(64, 2) void attn_kernel(
    const int8_t* __restrict__ qq, const int8_t* __restrict__ kq,
    const bf16_t* __restrict__ vdqt,
    const float* __restrict__ Fq, const float* __restrict__ Fk,
    const float* __restrict__ A2v, float* __restrict__ oattn)
{
  const int bh = blockIdx.x, b = bh >> 5, h = bh & 31;
  const int lane = threadIdx.x & 63;
  const int l31 = lane & 31, hi = lane >> 5;
  const int u = 31 - (int)blockIdx.y;
  const int q0 = u * 32;
  const int nt = u + 1;
  const size_t bhS = (size_t)bh * Ss;

  const int8_t* qrow = qq + (bhS + q0 + l31) * Dh + hi * 16;
  i32x4 qf[4];
#pragma unroll
  for (int c = 0; c < 4; ++c) qf[c] = *(const i32x4*)(qrow + c * 32);
  const float fq = Fq[bhS + q0 + l31];
  const int qcol = q0 + l31;

  float m = NEG_INF_F;
  int t = 0;
  for (; t + 1 < nt; t += 2) {
    const int kb0 = t * 32, kb1 = kb0 + 32;
    const int8_t* kr0 = kq + (bhS + kb0 + l31) * Dh + hi * 16;
    const int8_t* kr1 = kq + (bhS + kb1 + l31) * Dh + hi * 16;
    i32x16 ca = {}, cb = {}, da = {}, db = {};
    ca = __builtin_amdgcn_mfma_i32_32x32x32_i8(*(const i32x4*)(kr0),      qf[0], ca, 0, 0, 0);
    cb = __builtin_amdgcn_mfma_i32_32x32x32_i8(*(const i32x4*)(kr0 + 64), qf[2], cb, 0, 0, 0);
    da = __builtin_amdgcn_mfma_i32_32x32x32_i8(*(const i32x4*)(kr1),      qf[0], da, 0, 0, 0);
    db = __builtin_amdgcn_mfma_i32_32x32x32_i8(*(const i32x4*)(kr1 + 64), qf[2], db, 0, 0, 0);
    ca = __builtin_amdgcn_mfma_i32_32x32x32_i8(*(const i32x4*)(kr0 + 32), qf[1], ca, 0, 0, 0);
    cb = __builtin_amdgcn_mfma_i32_32x32x32_i8(*(const i32x4*)(kr0 + 96), qf[3], cb, 0, 0, 0);
    da = __builtin_amdgcn_mfma_i32_32x32x32_i8(*(const i32x4*)(kr1 + 32), qf[1], da, 0, 0, 0);
    db = __builtin_amdgcn_mfma_i32_32x32x32_i8(*(const i32x4*)(kr1 + 96), qf[3], db, 0, 0, 0);
    float4 fk40[4], fk41[4];
#pragma unroll
    for (int g = 0; g < 4; ++g) fk40[g] = *(const float4*)&Fk[bhS + kb0 + g * 8 + 4 * hi];
#pragma unroll
    for (int g = 0; g < 4; ++g) fk41[g] = *(const float4*)&Fk[bhS + kb1 + g * 8 + 4 * hi];
    const bool diag1 = (t + 1 == nt - 1);
#pragma unroll
    for (int r = 0; r < 16; ++r) {
      m = fmaxf(m, (float)(ca[r] + cb[r]) * fq * ((const float*)&fk40[r >> 2])[r & 3]);
      const float v1 = (float)(da[r] + db[r]) * fq * ((const float*)&fk41[r >> 2])[r & 3];
      if (!diag1 || (kb1 + KR(r) <= qcol)) m = fmaxf(m, v1);
    }
  }
  if (t < nt) {
    const int kb = t * 32;
    const int8_t* krow = kq + (bhS + kb + l31) * Dh + hi * 16;
    i32x16 ca = {}, cb = {};
    ca = __builtin_amdgcn_mfma_i32_32x32x32_i8(*(const i32x4*)(krow),      qf[0], ca, 0, 0, 0);
    cb = __builtin_amdgcn_mfma_i32_32x32x32_i8(*(const i32x4*)(krow + 64), qf[2], cb, 0, 0, 0);
    ca = __builtin_amdgcn_mfma_i32_32x32x32_i8(*(const i32x4*)(krow + 32), qf[1], ca, 0, 0, 0);
    cb = __builtin_amdgcn_mfma_i32_32x32x32_i8(*(const i32x4*)(krow + 96), qf[3], cb, 0, 0, 0);
    float4 fk4[4];
#pragma unroll
    for (int g = 0; g < 4; ++g) fk4[g] = *(const float4*)&Fk[bhS + kb + g * 8 + 4 * hi];
#pragma unroll
    for (int r = 0; r < 16; ++r) {
      const float v = (float)(ca[r] + cb[r]) * fq * ((const float*)&fk4[r >> 2])[r & 3];
      if (kb + KR(r) <= qcol) m = fmaxf(m, v);
    }
  }
  m = fmaxf(m, __shfl_xor(m, 32));

  float z = 0.f;
  f32x16 oacc[4] = {};
  for (int tt = 0; tt < nt; ++tt) {
    const int kb = tt * 32;
    const int8_t* krow = kq + (bhS + kb + l31) * Dh + hi * 16;
    i32x16 ca = {}, cb = {};
    ca = __builtin_amdgcn_mfma_i32_32x32x32_i8(*(const i32x4*)(krow),      qf[0], ca, 0, 0, 0);
    cb = __builtin_amdgcn_mfma_i32_32x32x32_i8(*(const i32x4*)(krow + 64), qf[2], cb, 0, 0, 0);
    ca = __builtin_amdgcn_mfma_i32_32x32x32_i8(*(const i32x4*)(krow + 32), qf[1], ca, 0, 0, 0);
    cb = __builtin_amdgcn_mfma_i32_32x32x32_i8(*(const i32x4*)(krow + 96), qf[3], cb, 0, 0, 0);
    float4 fk4[4];
#pragma unroll
    for (int g = 0; g < 4; ++g) fk4[g] = *(const float4*)&Fk[bhS + kb + g * 8 + 4 * hi];
    float p[16];
    const bool diag = (tt == nt - 1);
#pragma unroll
    for (int r = 0; r < 16; ++r) {
      float v = (float)(ca[r] + cb[r]) * fq * ((const float*)&fk4[r >> 2])[r & 3];
      if (diag && (kb + KR(r) > qcol)) v = NEG_INF_F;
      const float e = __expf(v - m);
      z += e;
      p[r] = rintf(127.0f * e);
    }
#pragma unroll
    for (int s = 0; s < 2; ++s) {
      const int rs = s * 8;
      unsigned k0 = pkbf(p[rs + 0], p[rs + 1]);
      unsigned k1 = pkbf(p[rs + 2], p[rs + 3]);
      unsigned k2 = pkbf(p[rs + 4], p[rs + 5]);
      unsigned k3 = pkbf(p[rs + 6], p[rs + 7]);
      unsigned sx0 = __shfl_xor(k0, 32);
      unsigned sx1 = __shfl_xor(k1, 32);
      unsigned sx2 = __shfl_xor(k2, 32);
      unsigned sx3 = __shfl_xor(k3, 32);
      uint4 ww;
      ww.x = hi ? sx2 : k0;
      ww.y = hi ? sx3 : k1;
      ww.z = hi ? k2 : sx0;
      ww.w = hi ? k3 : sx1;
      const bf16x8 af = __builtin_bit_cast(bf16x8, ww);
      const int kg2 = kb + s * 16 + hi * 8;
#pragma unroll
      for (int dt = 0; dt < 4; ++dt) {
        const bf16x8 vf = *(const bf16x8*)(vdqt + ((size_t)bh * Dh + dt * 32 + l31) * Ss + kg2);
        oacc[dt] = __builtin_amdgcn_mfma_f32_32x32x16_bf16(af, vf, oacc[dt], 0, 0, 0);
      }
    }
  }
  z += __shfl_xor(z, 32);
  const float osc = (1.0f / z) / 127.0f / A2v[bhS + q0 + l31];
#pragma unroll
  for (int dt = 0; dt < 4; ++dt) {
#pragma unroll
    for (int r = 0; r < 16; ++r) {
      const int q = q0 + KR(r);
      const float oscr = __shfl(osc, KR(r));
      oattn[((size_t)b * Ss + q) * Hid + h * Dh + dt * 32 + l31] = oacc[dt][r] * oscr;
    }
  }
}

extern "C" void kernel_launch(void* const* d_in, const int* in_sizes, int n_in,
                              void* d_out, int out_size, void* d_ws, size_t ws_size,
                              hipStream_t stream)
{
  const float* hidden = (const float*)d_in[0];
  const float* wq = (const float*)d_in[1];
  const float* wk = (const float*)d_in[2];
  const float* wv = (const float*)d_in[3];
  const float* wo = (const float*)d_in[4];
  float* out = (float*)d_out;

  char* p = (char*)d_ws;
  auto alloc = [&](size_t bytes) -> char* {
    char* r = p; p += (bytes + 255) & ~(size_t)255; return r;
  };
  int8_t* xq   = (int8_t*)alloc((size_t)Mr * Hid);       // later reused for oq
  int8_t* wb0  = (int8_t*)alloc((size_t)Hid * Hid);      // wq codes; later wo codes
  int8_t* wb1  = (int8_t*)alloc((size_t)Hid * Hid);      // wk codes
  int8_t* wb2  = (int8_t*)alloc((size_t)Hid * Hid);      // wv codes
  float*  oat  = (float*) alloc((size_t)Bh * Ss * Dh * sizeof(float));
  int8_t* qqb  = (int8_t*)alloc((size_t)Bh * Ss * Dh);
  int8_t* kqb  = (int8_t*)alloc((size_t)Bh * Ss * Dh);
  bf16_t* vdqt = (bf16_t*)alloc((size_t)Bh * Dh * Ss * sizeof(bf16_t));
  float* sxa = (float*)alloc((size_t)Mr * sizeof(float));
  float* sw0 = (float*)alloc((size_t)Hid * sizeof(float));
  float* sw1 = (float*)alloc((size_t)Hid * sizeof(float));
  float* sw2 = (float*)alloc((size_t)Hid * sizeof(float));
  float* Fq  = (float*)alloc((size_t)Bh * Ss * sizeof(float));
  float* Fk  = (float*)alloc((size_t)Bh * Ss * sizeof(float));
  float* A2v = (float*)alloc((size_t)Bh * Ss * sizeof(float));
  float* soa = (float*)alloc((size_t)Mr * sizeof(float));
  float* ctab = (float*)alloc((size_t)Ss * 64 * sizeof(float));
  float* stab = (float*)alloc((size_t)Ss * 64 * sizeof(float));
  int8_t* oq  = xq;   // xq dead after QKV GEMM

  rope_table_kernel<<<Ss * 64 / 256, 256, 0, stream>>>(ctab, stab);
  quant_rows_kernel<<<Mr, 256, 0, stream>>>(hidden, xq, sxa, Hid, 127.f, -128.f, 127.f);
  quant_w3_kernel<<<3 * Hid, 256, 0, stream>>>(wq, wk, wv, wb0, wb1, wb2, sw0, sw1, sw2);

  qkv_gemm_kernel<<<1536, 256, 0, stream>>>(xq, sxa, wb0, wb1, wb2, sw0, sw1, sw2,
                                            qqb, Fq, kqb, Fk, vdqt, A2v, ctab, stab);

  dim3 ga(Bh, 32);
  attn_kernel<<<ga, 64, 0, stream>>>(qqb, kqb, vdqt, Fq, Fk, A2v, oat);

  quant_rows_kernel<<<Mr, 256, 0, stream>>>(oat, oq, soa, Hid, 127.f, -128.f, 127.f);
  quant_rows_kernel<<<Hid, 256, 0, stream>>>(wo, wb0, sw0, Hid, 7.f, -8.f, 7.f);
  gemm0_kernel<<<512, 256, 0, stream>>>(oq, soa, wb0, sw0, out, Mr, Hid, Hid);
}